// Round 1
// baseline (22112.679 us; speedup 1.0000x reference)
//
#include <hip/hip_runtime.h>
#include <hip/hip_bf16.h>
#include <math.h>

// Problem constants (fixed by setup_inputs)
constexpr int B_  = 2;
constexpr int S_  = 1024;
constexpr int H_  = 1024;
constexpr int NH_ = 16;
constexpr int HD_ = 64;
constexpr int I_  = 4096;
constexpr int L_  = 4;
constexpr int M_  = B_ * S_;      // 2048 token rows
constexpr float EPS_ = 1e-6f;
constexpr int NUM_ITERS_ = 2;     // setup_inputs()["num_iterations"] == 2 (fixed input)

// ---------------------------------------------------------------------------
// Block reductions (wave64 shuffle + LDS across waves)
// ---------------------------------------------------------------------------
__device__ inline float block_reduce_sum(float v) {
    __shared__ float red[8];
    int lane = threadIdx.x & 63, wid = threadIdx.x >> 6;
#pragma unroll
    for (int o = 32; o; o >>= 1) v += __shfl_down(v, o);
    __syncthreads();
    if (lane == 0) red[wid] = v;
    __syncthreads();
    float s = 0.f;
    int nw = blockDim.x >> 6;
    for (int i = 0; i < nw; ++i) s += red[i];
    return s;
}

__device__ inline float block_reduce_max(float v) {
    __shared__ float red[8];
    int lane = threadIdx.x & 63, wid = threadIdx.x >> 6;
#pragma unroll
    for (int o = 32; o; o >>= 1) v = fmaxf(v, __shfl_down(v, o));
    __syncthreads();
    if (lane == 0) red[wid] = v;
    __syncthreads();
    float s = -INFINITY;
    int nw = blockDim.x >> 6;
    for (int i = 0; i < nw; ++i) s = fmaxf(s, red[i]);
    return s;
}

// ---------------------------------------------------------------------------
// Generic strided / batched fp32 GEMM: C = A @ B
// A[m,k] at A[m*rsA + k*csA], B[k,n] at B[k*rsB + n*csB], C[m,n] likewise.
// Batch index z = bb*NHb + hb with independent (b,h) strides per operand.
// 64x64 tile, BK=16, 256 threads, 4x4 per thread.
// ---------------------------------------------------------------------------
constexpr int BM_ = 64, BN_ = 64, BK_ = 16;

__global__ __launch_bounds__(256)
void gemm_f32(const float* __restrict__ A, const float* __restrict__ Bm,
              float* __restrict__ C,
              int M, int N, int K,
              long rsA, long csA, long rsB, long csB, long rsC, long csC,
              int NHb,
              long sbAb, long sbAh, long sbBb, long sbBh, long sbCb, long sbCh)
{
    int z  = blockIdx.z;
    int hb = z % NHb, bb = z / NHb;
    A  += (long)bb * sbAb + (long)hb * sbAh;
    Bm += (long)bb * sbBb + (long)hb * sbBh;
    C  += (long)bb * sbCb + (long)hb * sbCh;

    __shared__ float As[BK_][BM_ + 4];   // +4 pad keeps 16B alignment for b128 reads
    __shared__ float Bs[BK_][BN_ + 4];

    int tid = threadIdx.x;
    int tr = tid >> 4;        // 0..15 (row group)
    int tc = tid & 15;        // 0..15 (col group)
    int bm = blockIdx.y * BM_, bn = blockIdx.x * BN_;

    float acc[4][4] = {};

    for (int k0 = 0; k0 < K; k0 += BK_) {
        // ---- load A tile ----
        if (csA == 1) {
            // contiguous in k: 16-float runs per row
            for (int i = tid; i < BK_ * BM_; i += 256) {
                int kk = i & (BK_ - 1), mm = i >> 4;
                int gm = bm + mm, gk = k0 + kk;
                As[kk][mm] = (gm < M && gk < K) ? A[(long)gm * rsA + (long)gk * csA] : 0.f;
            }
        } else {
            for (int i = tid; i < BK_ * BM_; i += 256) {
                int mm = i & (BM_ - 1), kk = i >> 6;
                int gm = bm + mm, gk = k0 + kk;
                As[kk][mm] = (gm < M && gk < K) ? A[(long)gm * rsA + (long)gk * csA] : 0.f;
            }
        }
        // ---- load B tile ----
        if (csB == 1) {
            // contiguous in n: fully coalesced rows
            for (int i = tid; i < BK_ * BN_; i += 256) {
                int nn = i & (BN_ - 1), kk = i >> 6;
                int gn = bn + nn, gk = k0 + kk;
                Bs[kk][nn] = (gn < N && gk < K) ? Bm[(long)gk * rsB + (long)gn * csB] : 0.f;
            }
        } else {
            // contiguous in k
            for (int i = tid; i < BK_ * BN_; i += 256) {
                int kk = i & (BK_ - 1), nn = i >> 4;
                int gn = bn + nn, gk = k0 + kk;
                Bs[kk][nn] = (gn < N && gk < K) ? Bm[(long)gk * rsB + (long)gn * csB] : 0.f;
            }
        }
        __syncthreads();

#pragma unroll
        for (int kk = 0; kk < BK_; ++kk) {
            float a[4], b[4];
#pragma unroll
            for (int i = 0; i < 4; ++i) a[i] = As[kk][tr * 4 + i];
#pragma unroll
            for (int j = 0; j < 4; ++j) b[j] = Bs[kk][tc * 4 + j];
#pragma unroll
            for (int i = 0; i < 4; ++i)
#pragma unroll
                for (int j = 0; j < 4; ++j)
                    acc[i][j] += a[i] * b[j];
        }
        __syncthreads();
    }

#pragma unroll
    for (int i = 0; i < 4; ++i) {
        int gm = bm + tr * 4 + i;
        if (gm >= M) continue;
#pragma unroll
        for (int j = 0; j < 4; ++j) {
            int gn = bn + tc * 4 + j;
            if (gn >= N) continue;
            C[(long)gm * rsC + (long)gn * csC] = acc[i][j];
        }
    }
}

// ---------------------------------------------------------------------------
// RMSNorm: out[row] = (x+res) * rsqrt(mean((x+res)^2) + eps) * w   (H=1024)
// one block (256 threads) per row, 4 elements per thread
// ---------------------------------------------------------------------------
__global__ __launch_bounds__(256)
void rmsnorm_kernel(const float* __restrict__ x, const float* __restrict__ res,
                    const float* __restrict__ w, float* __restrict__ out)
{
    long row = blockIdx.x;
    const float* xr = x + row * H_;
    const float* rr = res ? res + row * H_ : nullptr;
    float v[4];
    float ss = 0.f;
#pragma unroll
    for (int i = 0; i < 4; ++i) {
        int idx = threadIdx.x + i * 256;
        float t = xr[idx];
        if (rr) t += rr[idx];
        v[i] = t;
        ss += t * t;
    }
    ss = block_reduce_sum(ss);
    float inv = rsqrtf(ss * (1.f / H_) + EPS_);
    float* orow = out + row * H_;
#pragma unroll
    for (int i = 0; i < 4; ++i) {
        int idx = threadIdx.x + i * 256;
        orow[idx] = v[i] * inv * w[idx];
    }
}

// ---------------------------------------------------------------------------
// Causal softmax over score rows (in-place). blockIdx.x indexes (b,h,q).
// Masked (k > q) entries are written as 0 so PV can be a dense GEMM.
// ---------------------------------------------------------------------------
__global__ __launch_bounds__(256)
void softmax_causal(float* __restrict__ scores, float scale)
{
    long r = blockIdx.x;                 // 0 .. B*NH*S-1
    int q = (int)(r % S_);
    float* row = scores + r * (long)S_;
    __shared__ float buf[S_];

    float m = -INFINITY;
    for (int i = threadIdx.x; i <= q; i += 256) {
        float t = row[i] * scale;
        buf[i] = t;
        m = fmaxf(m, t);
    }
    m = block_reduce_max(m);

    float sum = 0.f;
    for (int i = threadIdx.x; i <= q; i += 256) {
        float e = expf(buf[i] - m);
        buf[i] = e;
        sum += e;
    }
    sum = block_reduce_sum(sum);
    float inv = 1.f / sum;

    for (int i = threadIdx.x; i < S_; i += 256) {
        row[i] = (i <= q) ? buf[i] * inv : 0.f;
    }
}

// ---------------------------------------------------------------------------
// concat: cat[m, :H] = E[m], cat[m, H:2H] = state[m]
// ---------------------------------------------------------------------------
__global__ __launch_bounds__(256)
void concat_kernel(const float* __restrict__ E, const float* __restrict__ st,
                   float* __restrict__ cat)
{
    long n = (long)M_ * 2 * H_;
    for (long i = (long)blockIdx.x * blockDim.x + threadIdx.x; i < n;
         i += (long)gridDim.x * blockDim.x) {
        long m = i / (2 * H_);
        long c = i % (2 * H_);
        cat[i] = (c < H_) ? E[m * H_ + c] : st[m * H_ + (c - H_)];
    }
}

// ---------------------------------------------------------------------------
// silu-gate: g[m,i] = silu(h[m,i]) * h[m, I+i]   (h is [M, 2I])
// ---------------------------------------------------------------------------
__global__ __launch_bounds__(256)
void silu_gate(const float* __restrict__ h, float* __restrict__ g)
{
    long n = (long)M_ * I_;
    for (long i = (long)blockIdx.x * blockDim.x + threadIdx.x; i < n;
         i += (long)gridDim.x * blockDim.x) {
        long m = i / I_;
        long c = i % I_;
        float gate = h[m * (2 * I_) + c];
        float val  = h[m * (2 * I_) + I_ + c];
        float s = gate / (1.f + expf(-gate));
        g[i] = s * val;
    }
}

// ---------------------------------------------------------------------------
// Host-side launcher
// ---------------------------------------------------------------------------
static inline void launch_gemm(hipStream_t st,
                               const float* A, const float* B, float* C,
                               int M, int N, int K,
                               long rsA, long csA, long rsB, long csB,
                               long rsC, long csC,
                               int nb = 1, int nh = 1,
                               long sbAb = 0, long sbAh = 0,
                               long sbBb = 0, long sbBh = 0,
                               long sbCb = 0, long sbCh = 0)
{
    dim3 grid((N + BN_ - 1) / BN_, (M + BM_ - 1) / BM_, nb * nh);
    gemm_f32<<<grid, dim3(256), 0, st>>>(A, B, C, M, N, K,
                                         rsA, csA, rsB, csB, rsC, csC,
                                         nh, sbAb, sbAh, sbBb, sbBh, sbCb, sbCh);
}

extern "C" void kernel_launch(void* const* d_in, const int* in_sizes, int n_in,
                              void* d_out, int out_size, void* d_ws, size_t ws_size,
                              hipStream_t stream)
{
    const float* E   = (const float*)d_in[0];
    const float* st0 = (const float*)d_in[1];
    const float* Wa  = (const float*)d_in[2];
    const float* NW  = (const float*)d_in[3];
    const float* Wq  = (const float*)d_in[4];
    const float* Wk  = (const float*)d_in[5];
    const float* Wv  = (const float*)d_in[6];
    const float* Wo  = (const float*)d_in[7];
    const float* W1  = (const float*)d_in[8];
    const float* W2  = (const float*)d_in[9];
    const float* FNW = (const float*)d_in[10];
    float* out = (float*)d_out;

    // ---- workspace arena ----
    char* base = (char*)d_ws;
    size_t off = 0;
    auto alloc = [&](size_t elems) -> float* {
        float* p = (float*)(base + off);
        off += ((elems * sizeof(float)) + 255) & ~(size_t)255;
        return p;
    };
    float* cat    = alloc((size_t)M_ * 2 * H_);          // 16 MB
    float* x      = alloc((size_t)M_ * H_);              // 8 MB
    float* xn     = alloc((size_t)M_ * H_);              // 8 MB
    float* qb     = alloc((size_t)M_ * H_);              // 8 MB
    float* kb     = alloc((size_t)M_ * H_);              // 8 MB
    float* vb     = alloc((size_t)M_ * H_);              // 8 MB
    float* ob     = alloc((size_t)M_ * H_);              // 8 MB
    float* aob    = alloc((size_t)M_ * H_);              // 8 MB (also reused for MLP out)
    float* scores = alloc((size_t)B_ * NH_ * S_ * S_);   // 134 MB
    // MLP buffers alias the (dead-by-then) scores region:
    float* hbuf = scores;                                 // [M, 2I] = 67 MB
    float* gbuf = scores + (size_t)M_ * 2 * I_;           // [M, I]  = 33.5 MB
    (void)ws_size; (void)in_sizes; (void)n_in; (void)out_size;

    const float scale = 0.125f;   // 1/sqrt(HD)

    const float* state = st0;
    for (int it = 0; it < NUM_ITERS_; ++it) {
        // x = concat(E, state) @ Wa
        concat_kernel<<<dim3(4096), dim3(256), 0, stream>>>(E, state, cat);
        launch_gemm(stream, cat, Wa, x, M_, H_, 2 * H_,
                    2 * H_, 1, H_, 1, H_, 1);

        for (int l = 0; l < L_; ++l) {
            const float* nw  = NW + (size_t)l * 4 * H_;
            const float* wq  = Wq + (size_t)l * H_ * H_;
            const float* wk  = Wk + (size_t)l * H_ * H_;
            const float* wv  = Wv + (size_t)l * H_ * H_;
            const float* wo  = Wo + (size_t)l * H_ * H_;
            const float* w1  = W1 + (size_t)l * H_ * 2 * I_;
            const float* w2  = W2 + (size_t)l * I_ * H_;

            // xn = rmsnorm(x, nw0)
            rmsnorm_kernel<<<M_, 256, 0, stream>>>(x, nullptr, nw + 0 * H_, xn);

            // q/k/v = xn @ W{q,k,v}
            launch_gemm(stream, xn, wq, qb, M_, H_, H_, H_, 1, H_, 1, H_, 1);
            launch_gemm(stream, xn, wk, kb, M_, H_, H_, H_, 1, H_, 1, H_, 1);
            launch_gemm(stream, xn, wv, vb, M_, H_, H_, H_, 1, H_, 1, H_, 1);

            // scores[b,h,q,k] = sum_d q[b,q,h,d] * k[b,k,h,d]
            launch_gemm(stream, qb, kb, scores, S_, S_, HD_,
                        /*A*/ H_, 1, /*B (k^T)*/ 1, H_, /*C*/ S_, 1,
                        B_, NH_,
                        (long)S_ * H_, HD_,
                        (long)S_ * H_, HD_,
                        (long)NH_ * S_ * S_, (long)S_ * S_);

            // causal softmax (in-place, masked entries -> 0)
            softmax_causal<<<B_ * NH_ * S_, 256, 0, stream>>>(scores, scale);

            // o[b,q,h,d] = sum_k attn[b,h,q,k] * v[b,k,h,d]
            launch_gemm(stream, scores, vb, ob, S_, HD_, S_,
                        /*A*/ S_, 1, /*B*/ H_, 1, /*C*/ H_, 1,
                        B_, NH_,
                        (long)NH_ * S_ * S_, (long)S_ * S_,
                        (long)S_ * H_, HD_,
                        (long)S_ * H_, HD_);

            // attn_out = o @ Wo
            launch_gemm(stream, ob, wo, aob, M_, H_, H_, H_, 1, H_, 1, H_, 1);

            // x = rmsnorm(x + attn_out, nw1)   (in-place safe: per-row regs)
            rmsnorm_kernel<<<M_, 256, 0, stream>>>(x, aob, nw + 1 * H_, x);

            // xn = rmsnorm(x, nw2)
            rmsnorm_kernel<<<M_, 256, 0, stream>>>(x, nullptr, nw + 2 * H_, xn);

            // hbuf = xn @ W1   [M, 2I]
            launch_gemm(stream, xn, w1, hbuf, M_, 2 * I_, H_,
                        H_, 1, 2 * I_, 1, 2 * I_, 1);

            // gbuf = silu(gate) * val
            silu_gate<<<dim3(8192), dim3(256), 0, stream>>>(hbuf, gbuf);

            // mlp_out = gbuf @ W2  (reuse aob)
            launch_gemm(stream, gbuf, w2, aob, M_, H_, I_,
                        I_, 1, H_, 1, H_, 1);

            // x = rmsnorm(x + mlp_out, nw3)
            rmsnorm_kernel<<<M_, 256, 0, stream>>>(x, aob, nw + 3 * H_, x);
        }
        state = x;   // next iteration concatenates against updated state
    }

    // out = rmsnorm(state, final_norm_w)
    rmsnorm_kernel<<<M_, 256, 0, stream>>>(x, nullptr, FNW, out);
}

// Round 4
// 3056.230 us; speedup vs baseline: 7.2353x; 7.2353x over previous
//
#include <hip/hip_runtime.h>
#include <hip/hip_bf16.h>
#include <math.h>

// Problem constants (fixed by setup_inputs)
constexpr int B_  = 2;
constexpr int S_  = 1024;
constexpr int H_  = 1024;
constexpr int NH_ = 16;
constexpr int HD_ = 64;
constexpr int I_  = 4096;
constexpr int L_  = 4;
constexpr int M_  = B_ * S_;      // 2048 token rows
constexpr float EPS_ = 1e-6f;
constexpr int NUM_ITERS_ = 2;     // setup_inputs()["num_iterations"] == 2 (fixed input)

typedef __attribute__((ext_vector_type(8))) short bf16x8;
typedef __attribute__((ext_vector_type(4))) float f32x4;

__device__ __forceinline__ short f2b(float x) {
    return __builtin_bit_cast(short, __float2bfloat16(x));
}
__device__ __forceinline__ float b2f(short s) {
    return __builtin_bit_cast(float, ((unsigned)(unsigned short)s) << 16);
}

__device__ __forceinline__ void lds_load16(void* lds, const void* g) {
    __builtin_amdgcn_global_load_lds(
        (const __attribute__((address_space(1))) void*)g,
        (__attribute__((address_space(3))) void*)lds, 16, 0, 0);
}

// ---------------------------------------------------------------------------
// Block reductions (wave64 shuffle + LDS across waves, blockDim = 256)
// ---------------------------------------------------------------------------
__device__ inline float block_reduce_sum(float v) {
    __shared__ float red[8];
    int lane = threadIdx.x & 63, wid = threadIdx.x >> 6;
#pragma unroll
    for (int o = 32; o; o >>= 1) v += __shfl_down(v, o);
    __syncthreads();
    if (lane == 0) red[wid] = v;
    __syncthreads();
    float s = 0.f;
    for (int i = 0; i < 4; ++i) s += red[i];
    return s;
}

__device__ inline float block_reduce_max(float v) {
    __shared__ float red[8];
    int lane = threadIdx.x & 63, wid = threadIdx.x >> 6;
#pragma unroll
    for (int o = 32; o; o >>= 1) v = fmaxf(v, __shfl_down(v, o));
    __syncthreads();
    if (lane == 0) red[wid] = v;
    __syncthreads();
    float s = -INFINITY;
    for (int i = 0; i < 4; ++i) s = fmaxf(s, red[i]);
    return s;
}

// ---------------------------------------------------------------------------
// bf16 MFMA GEMM (m97 structure): C[M,N] = A[M,K] @ B^T[N,K]^T
// A row-major (lda), Bt row-major (ldb), C row-major (ldc).
// 256 threads = 4 waves (2x2), tile BM x BN, BK=32, 16x16x32 MFMA.
// global_load_lds width-16 staging; k-slot XOR swizzle by (row>>1)&3
// (source-side pre-swizzle + matching ds_read side) -> 2-way bank alias (free).
// Batched over z = bb*NHb + hb with independent strides.
// Requires: M%BM==0, N%BN==0, K%32==0, lda/ldb multiples of 8, 16B-aligned ptrs.
// ---------------------------------------------------------------------------
template<int BM, int BN, typename OutT>
__global__ __launch_bounds__(256)
void gemm_mfma(const __hip_bfloat16* __restrict__ A,
               const __hip_bfloat16* __restrict__ Bt,
               OutT* __restrict__ C,
               int K, int lda, int ldb, int ldc,
               int NHb,
               long sAb, long sAh, long sBb, long sBh, long sCb, long sCh)
{
    int z = blockIdx.z;
    int hb = z % NHb, bb = z / NHb;
    A  += bb * sAb + hb * sAh;
    Bt += bb * sBb + hb * sBh;
    C  += bb * sCb + hb * sCh;

    int bm = blockIdx.y * BM, bn = blockIdx.x * BN;

    __shared__ __align__(16) char smemA[BM * 64];   // [BM][32] bf16
    __shared__ __align__(16) char smemB[BN * 64];   // [BN][32] bf16

    const int t    = threadIdx.x;
    const int lane = t & 63;
    const int wv   = t >> 6;
    // staging: thread t covers row lr (within a 64-row chunk), swizzled k-slot
    const int lr  = t >> 2;                            // 0..63
    const int lsw = ((t & 3) ^ ((lr >> 1) & 3)) * 8;   // element offset in k

    constexpr int FM = BM / 32;   // 16-row frags per wave in M (wave tile = BM/2)
    constexpr int FN = BN / 32;
    const int wm = (wv >> 1) * (BM / 2);
    const int wn = (wv & 1) * (BN / 2);
    const int row16 = lane & 15;
    const int kg    = lane >> 4;

    f32x4 acc[FM][FN] = {};

    const char* Ab = (const char*)A;
    const char* Bb = (const char*)Bt;

    for (int k0 = 0; k0 < K; k0 += 32) {
#pragma unroll
        for (int i = 0; i < BM / 64; ++i)
            lds_load16(smemA + i * 4096 + wv * 1024,
                       Ab + (((long)(bm + i * 64 + lr) * lda + k0 + lsw) << 1));
#pragma unroll
        for (int i = 0; i < BN / 64; ++i)
            lds_load16(smemB + i * 4096 + wv * 1024,
                       Bb + (((long)(bn + i * 64 + lr) * ldb + k0 + lsw) << 1));
        __syncthreads();

        bf16x8 af[FM], bfr[FN];
#pragma unroll
        for (int m = 0; m < FM; ++m) {
            int r = wm + m * 16 + row16;
            af[m] = *(const bf16x8*)(smemA + r * 64 + ((kg ^ ((r >> 1) & 3)) << 4));
        }
#pragma unroll
        for (int n = 0; n < FN; ++n) {
            int r = wn + n * 16 + row16;
            bfr[n] = *(const bf16x8*)(smemB + r * 64 + ((kg ^ ((r >> 1) & 3)) << 4));
        }
#pragma unroll
        for (int m = 0; m < FM; ++m)
#pragma unroll
            for (int n = 0; n < FN; ++n)
                acc[m][n] = __builtin_amdgcn_mfma_f32_16x16x32_bf16(
                                af[m], bfr[n], acc[m][n], 0, 0, 0);
        __syncthreads();
    }

    // epilogue: D row = (lane>>4)*4 + reg, col = lane&15  [m89/m91 layout]
#pragma unroll
    for (int m = 0; m < FM; ++m) {
#pragma unroll
        for (int n = 0; n < FN; ++n) {
#pragma unroll
            for (int r = 0; r < 4; ++r) {
                long row = bm + wm + m * 16 + kg * 4 + r;
                long col = bn + wn + n * 16 + row16;
                float val = acc[m][n][r];
                if constexpr (__is_same(OutT, __hip_bfloat16))
                    C[row * ldc + col] = __float2bfloat16(val);
                else
                    C[row * ldc + col] = val;
            }
        }
    }
}

template<int BM, int BN, typename OutT>
static inline void launch_mm(hipStream_t st,
                             const __hip_bfloat16* A, const __hip_bfloat16* Bt, OutT* C,
                             int M, int N, int K, int lda, int ldb, int ldc,
                             int nb = 1, int nh = 1,
                             long sAb = 0, long sAh = 0,
                             long sBb = 0, long sBh = 0,
                             long sCb = 0, long sCh = 0)
{
    dim3 grid(N / BN, M / BM, nb * nh);
    gemm_mfma<BM, BN, OutT><<<grid, dim3(256), 0, st>>>(
        A, Bt, C, K, lda, ldb, ldc, nh, sAb, sAh, sBb, sBh, sCb, sCh);
}

// ---------------------------------------------------------------------------
// Weight transpose + fp32->bf16: out[c][r] = (bf16)in[r][c]; in is [R][C]
// grid: (C/32, R/32, nz); 256 threads. R,C multiples of 32.
// ---------------------------------------------------------------------------
__global__ __launch_bounds__(256)
void transpose_w(const float* __restrict__ in, __hip_bfloat16* __restrict__ out,
                 int R, int C, long inz, long outz)
{
    in  += blockIdx.z * inz;
    out += blockIdx.z * outz;
    __shared__ float tile[32][33];
    int rb = blockIdx.y * 32, cb = blockIdx.x * 32;
    int tx = threadIdx.x & 31, ty = threadIdx.x >> 5;   // ty 0..7
#pragma unroll
    for (int i = 0; i < 32; i += 8)
        tile[ty + i][tx] = in[(long)(rb + ty + i) * C + cb + tx];
    __syncthreads();
#pragma unroll
    for (int i = 0; i < 32; i += 8)
        out[(long)(cb + ty + i) * R + rb + tx] = __float2bfloat16(tile[tx][ty + i]);
}

// ---------------------------------------------------------------------------
// V transpose per head: vT[z][d][s] = src[b*S+s][h*64+d], z = b*NH+h (bf16)
// src has row stride ldsrc. grid: (S/32, 64/32, B*NH); 256 threads
// ---------------------------------------------------------------------------
__global__ __launch_bounds__(256)
void transpose_v(const __hip_bfloat16* __restrict__ v, __hip_bfloat16* __restrict__ vT,
                 int ldsrc)
{
    int z = blockIdx.z, b = z >> 4, h = z & 15;
    __shared__ short tile[32][34];
    int sb = blockIdx.x * 32, db = blockIdx.y * 32;
    int tx = threadIdx.x & 31, ty = threadIdx.x >> 5;
    const __hip_bfloat16* src = v + (long)b * S_ * ldsrc + h * 64;
#pragma unroll
    for (int i = 0; i < 32; i += 8)
        tile[ty + i][tx] = __builtin_bit_cast(short, src[(long)(sb + ty + i) * ldsrc + db + tx]);
    __syncthreads();
    __hip_bfloat16* dst = vT + (long)z * 64 * S_;
#pragma unroll
    for (int i = 0; i < 32; i += 8)
        dst[(long)(db + ty + i) * S_ + sb + tx] =
            __builtin_bit_cast(__hip_bfloat16, tile[tx][ty + i]);
}

// ---------------------------------------------------------------------------
// RMSNorm: out[row] = (x+res) * rsqrt(mean((x+res)^2)+eps) * w (H=1024)
// one block (256 threads) per row, float4 per thread; OutT fp32 or bf16
// ---------------------------------------------------------------------------
template<typename OutT>
__global__ __launch_bounds__(256)
void rmsnorm_k(const float* __restrict__ x, const float* __restrict__ res,
               const float* __restrict__ w, OutT* __restrict__ out)
{
    long row = blockIdx.x;
    int t = threadIdx.x;
    float4 v = *(const float4*)&x[row * H_ + t * 4];
    if (res) {
        float4 rv = *(const float4*)&res[row * H_ + t * 4];
        v.x += rv.x; v.y += rv.y; v.z += rv.z; v.w += rv.w;
    }
    float ss = v.x * v.x + v.y * v.y + v.z * v.z + v.w * v.w;
    ss = block_reduce_sum(ss);
    float inv = rsqrtf(ss * (1.f / H_) + EPS_);
    float4 wv = *(const float4*)&w[t * 4];
    float4 y = {v.x * inv * wv.x, v.y * inv * wv.y, v.z * inv * wv.z, v.w * inv * wv.w};
    if constexpr (__is_same(OutT, __hip_bfloat16)) {
        short4 o = {f2b(y.x), f2b(y.y), f2b(y.z), f2b(y.w)};
        *(short4*)&out[row * H_ + t * 4] = o;
    } else {
        *(float4*)&out[row * H_ + t * 4] = y;
    }
}

// Fused: x' = rmsnorm(x+res, w1) [fp32]; xn = rmsnorm(x', w2) [bf16]
__global__ __launch_bounds__(256)
void rmsnorm_dual(const float* __restrict__ x, const float* __restrict__ res,
                  const float* __restrict__ w1, const float* __restrict__ w2,
                  float* __restrict__ xout, __hip_bfloat16* __restrict__ xnout)
{
    long row = blockIdx.x;
    int t = threadIdx.x;
    float4 v = *(const float4*)&x[row * H_ + t * 4];
    float4 rv = *(const float4*)&res[row * H_ + t * 4];
    v.x += rv.x; v.y += rv.y; v.z += rv.z; v.w += rv.w;
    float ss = v.x * v.x + v.y * v.y + v.z * v.z + v.w * v.w;
    ss = block_reduce_sum(ss);
    float inv = rsqrtf(ss * (1.f / H_) + EPS_);
    float4 w1v = *(const float4*)&w1[t * 4];
    float4 y = {v.x * inv * w1v.x, v.y * inv * w1v.y, v.z * inv * w1v.z, v.w * inv * w1v.w};
    *(float4*)&xout[row * H_ + t * 4] = y;
    float ss2 = y.x * y.x + y.y * y.y + y.z * y.z + y.w * y.w;
    ss2 = block_reduce_sum(ss2);
    float inv2 = rsqrtf(ss2 * (1.f / H_) + EPS_);
    float4 w2v = *(const float4*)&w2[t * 4];
    short4 o = {f2b(y.x * inv2 * w2v.x), f2b(y.y * inv2 * w2v.y),
                f2b(y.z * inv2 * w2v.z), f2b(y.w * inv2 * w2v.w)};
    *(short4*)&xnout[row * H_ + t * 4] = o;
}

// ---------------------------------------------------------------------------
// Causal softmax over bf16 score rows (in-place). blockIdx.x = (b,h,q).
// thread t owns elements t*4..t*4+3 of the 1024-long row. Masked -> 0.
// ---------------------------------------------------------------------------
__global__ __launch_bounds__(256)
void softmax_causal_bf16(__hip_bfloat16* __restrict__ sc, float scale)
{
    long r = blockIdx.x;
    int q = (int)(r % S_);
    __hip_bfloat16* row = sc + r * (long)S_;
    int t = threadIdx.x;
    short4 raw = *(const short4*)&row[t * 4];
    float f[4];
    f[0] = b2f(raw.x) * scale; f[1] = b2f(raw.y) * scale;
    f[2] = b2f(raw.z) * scale; f[3] = b2f(raw.w) * scale;
    float m = -INFINITY;
#pragma unroll
    for (int j = 0; j < 4; ++j)
        if (t * 4 + j <= q) m = fmaxf(m, f[j]);
    m = block_reduce_max(m);
    float e[4], sum = 0.f;
#pragma unroll
    for (int j = 0; j < 4; ++j) {
        e[j] = (t * 4 + j <= q) ? expf(f[j] - m) : 0.f;
        sum += e[j];
    }
    sum = block_reduce_sum(sum);
    float inv = 1.f / sum;
    short4 o = {f2b(e[0] * inv), f2b(e[1] * inv), f2b(e[2] * inv), f2b(e[3] * inv)};
    *(short4*)&row[t * 4] = o;
}

// ---------------------------------------------------------------------------
// concat -> bf16: cat[m, :H]=E[m], cat[m, H:2H]=state[m]
// ---------------------------------------------------------------------------
__global__ __launch_bounds__(256)
void concat_bf16(const float* __restrict__ E, const float* __restrict__ st,
                 __hip_bfloat16* __restrict__ cat)
{
    long n4 = (long)M_ * 2 * H_ / 4;
    for (long i = (long)blockIdx.x * blockDim.x + threadIdx.x; i < n4;
         i += (long)gridDim.x * blockDim.x) {
        long m = i / (2 * H_ / 4);
        long c4 = i % (2 * H_ / 4);
        const float* src = (c4 < H_ / 4) ? &E[m * H_ + c4 * 4]
                                         : &st[m * H_ + (c4 * 4 - H_)];
        float4 v = *(const float4*)src;
        short4 o = {f2b(v.x), f2b(v.y), f2b(v.z), f2b(v.w)};
        *(short4*)&cat[i * 4] = o;
    }
}

// ---------------------------------------------------------------------------
// silu-gate: g[m,i] = (bf16) silu(h[m,i]) * h[m,I+i]; h fp32 [M,2I]
// ---------------------------------------------------------------------------
__global__ __launch_bounds__(256)
void silu_gate(const float* __restrict__ h, __hip_bfloat16* __restrict__ g)
{
    long n4 = (long)M_ * I_ / 4;
    for (long i = (long)blockIdx.x * blockDim.x + threadIdx.x; i < n4;
         i += (long)gridDim.x * blockDim.x) {
        long m = i / (I_ / 4);
        long c = (i % (I_ / 4)) * 4;
        float4 gt = *(const float4*)&h[m * (2 * I_) + c];
        float4 vl = *(const float4*)&h[m * (2 * I_) + I_ + c];
        float4 y;
        y.x = gt.x / (1.f + expf(-gt.x)) * vl.x;
        y.y = gt.y / (1.f + expf(-gt.y)) * vl.y;
        y.z = gt.z / (1.f + expf(-gt.z)) * vl.z;
        y.w = gt.w / (1.f + expf(-gt.w)) * vl.w;
        short4 o = {f2b(y.x), f2b(y.y), f2b(y.z), f2b(y.w)};
        *(short4*)&g[m * I_ + c] = o;
    }
}

// ---------------------------------------------------------------------------
// Host launcher
// ---------------------------------------------------------------------------
extern "C" void kernel_launch(void* const* d_in, const int* in_sizes, int n_in,
                              void* d_out, int out_size, void* d_ws, size_t ws_size,
                              hipStream_t stream)
{
    const float* E   = (const float*)d_in[0];
    const float* st0 = (const float*)d_in[1];
    const float* Wa  = (const float*)d_in[2];
    const float* NW  = (const float*)d_in[3];
    const float* Wq  = (const float*)d_in[4];
    const float* Wk  = (const float*)d_in[5];
    const float* Wv  = (const float*)d_in[6];
    const float* Wo  = (const float*)d_in[7];
    const float* W1  = (const float*)d_in[8];
    const float* W2  = (const float*)d_in[9];
    const float* FNW = (const float*)d_in[10];
    float* out = (float*)d_out;
    (void)in_sizes; (void)n_in; (void)out_size;

    typedef __hip_bfloat16 bf16;

    // Resident-weight layout needs 260 MB; fall back to per-layer W1/W2 staging
    // (188 MB, below the empirically-proven 206 MB ws floor) otherwise.
    const size_t RESIDENT_BYTES = 273000000;   // 260 MB + slack
    const bool resident = ws_size >= RESIDENT_BYTES;

    char* base = (char*)d_ws;
    size_t off = 0;
    auto alloc = [&](size_t bytes) -> char* {
        char* p = base + off;
        off += (bytes + 255) & ~(size_t)255;
        return p;
    };
    // bf16 transposed weights
    bf16* WaT   = (bf16*)alloc((size_t)H_ * 2 * H_ * 2);                    // [H][2H]   4 MB
    bf16* WqkvT = (bf16*)alloc((size_t)L_ * 3 * H_ * H_ * 2);               // [L][3H][H] 24 MB
    bf16* WoT   = (bf16*)alloc((size_t)L_ * H_ * H_ * 2);                   // 8 MB
    bf16* W1T   = (bf16*)alloc((resident ? (size_t)L_ : 1) * 2 * I_ * H_ * 2); // 64/16 MB
    bf16* W2T   = (bf16*)alloc((resident ? (size_t)L_ : 1) * H_ * I_ * 2);     // 32/8 MB
    // activations
    bf16*  cat  = (bf16*)alloc((size_t)M_ * 2 * H_ * 2);    // 8 MB
    float* x    = (float*)alloc((size_t)M_ * H_ * 4);       // 8 MB
    bf16*  xn   = (bf16*)alloc((size_t)M_ * H_ * 2);        // 4 MB
    bf16*  qkv  = (bf16*)alloc((size_t)M_ * 3 * H_ * 2);    // 12 MB [M][3H]
    bf16*  vT   = (bf16*)alloc((size_t)M_ * H_ * 2);        // 4 MB  [B*NH][64][S]
    bf16*  ob   = (bf16*)alloc((size_t)M_ * H_ * 2);        // 4 MB
    float* aob  = (float*)alloc((size_t)M_ * H_ * 4);       // 8 MB
    char*  scores_raw = alloc((size_t)B_ * NH_ * S_ * S_ * 2);  // 64 MB bf16
    bf16*  scores = (bf16*)scores_raw;
    float* hbuf   = (float*)scores_raw;   // [M][2I] fp32 = 64 MB, aliases scores
    bf16*  gbuf   = (bf16*)alloc((size_t)M_ * I_ * 2);      // 16 MB

    // ---- one-time weight conversion/transpose ----
    transpose_w<<<dim3(H_ / 32, 2 * H_ / 32, 1), 256, 0, stream>>>(
        Wa, WaT, 2 * H_, H_, 0, 0);
    // q/k/v sections of combined [3H][H] per layer
    transpose_w<<<dim3(H_ / 32, H_ / 32, L_), 256, 0, stream>>>(
        Wq, WqkvT + 0 * H_ * H_, H_, H_, (long)H_ * H_, (long)3 * H_ * H_);
    transpose_w<<<dim3(H_ / 32, H_ / 32, L_), 256, 0, stream>>>(
        Wk, WqkvT + 1 * H_ * H_, H_, H_, (long)H_ * H_, (long)3 * H_ * H_);
    transpose_w<<<dim3(H_ / 32, H_ / 32, L_), 256, 0, stream>>>(
        Wv, WqkvT + 2 * H_ * H_, H_, H_, (long)H_ * H_, (long)3 * H_ * H_);
    transpose_w<<<dim3(H_ / 32, H_ / 32, L_), 256, 0, stream>>>(
        Wo, WoT, H_, H_, (long)H_ * H_, (long)H_ * H_);
    if (resident) {
        transpose_w<<<dim3(2 * I_ / 32, H_ / 32, L_), 256, 0, stream>>>(
            W1, W1T, H_, 2 * I_, (long)H_ * 2 * I_, (long)H_ * 2 * I_);
        transpose_w<<<dim3(H_ / 32, I_ / 32, L_), 256, 0, stream>>>(
            W2, W2T, I_, H_, (long)I_ * H_, (long)I_ * H_);
    }

    const float scale = 0.125f;   // 1/sqrt(HD)
    const float* state = st0;

    for (int it = 0; it < NUM_ITERS_; ++it) {
        concat_bf16<<<dim3(4096), 256, 0, stream>>>(E, state, cat);
        // x = cat @ Wa   (fp32 out)
        launch_mm<128, 128, float>(stream, cat, WaT, x,
                                   M_, H_, 2 * H_, 2 * H_, 2 * H_, H_);

        for (int l = 0; l < L_; ++l) {
            const float* nw   = NW + (size_t)l * 4 * H_;
            const bf16* wqkvT = WqkvT + (size_t)l * 3 * H_ * H_;
            const bf16* woT   = WoT + (size_t)l * H_ * H_;
            const bf16* w1T;
            const bf16* w2T;
            if (resident) {
                w1T = W1T + (size_t)l * 2 * I_ * H_;
                w2T = W2T + (size_t)l * H_ * I_;
            } else {
                transpose_w<<<dim3(2 * I_ / 32, H_ / 32, 1), 256, 0, stream>>>(
                    W1 + (size_t)l * H_ * 2 * I_, W1T, H_, 2 * I_, 0, 0);
                transpose_w<<<dim3(H_ / 32, I_ / 32, 1), 256, 0, stream>>>(
                    W2 + (size_t)l * I_ * H_, W2T, I_, H_, 0, 0);
                w1T = W1T;
                w2T = W2T;
            }

            rmsnorm_k<bf16><<<M_, 256, 0, stream>>>(x, nullptr, nw + 0 * H_, xn);

            // fused qkv = xn @ [Wq|Wk|Wv]   (bf16 out, [M][3H])
            launch_mm<128, 128, bf16>(stream, xn, wqkvT, qkv,
                                      M_, 3 * H_, H_, H_, H_, 3 * H_);

            // scores[b,h,q,k] = q . k  (q = qkv cols 0..H, k = cols H..2H)
            launch_mm<128, 128, bf16>(stream, qkv, qkv + H_, scores,
                                      S_, S_, HD_, 3 * H_, 3 * H_, S_,
                                      B_, NH_,
                                      (long)S_ * 3 * H_, 64,
                                      (long)S_ * 3 * H_, 64,
                                      (long)NH_ * S_ * S_, (long)S_ * S_);

            softmax_causal_bf16<<<B_ * NH_ * S_, 256, 0, stream>>>(scores, scale);

            // vT[z][d][s] from v section (cols 2H..3H)
            transpose_v<<<dim3(S_ / 32, 2, B_ * NH_), 256, 0, stream>>>(
                qkv + 2 * H_, vT, 3 * H_);

            // ob[b,q,h*64+d] = probs @ v
            launch_mm<128, 64, bf16>(stream, scores, vT, ob,
                                     S_, 64, S_, S_, S_, H_,
                                     B_, NH_,
                                     (long)NH_ * S_ * S_, (long)S_ * S_,
                                     (long)NH_ * 64 * S_, (long)64 * S_,
                                     (long)S_ * H_, 64);

            // attn_out = ob @ Wo  (fp32)
            launch_mm<128, 128, float>(stream, ob, woT, aob, M_, H_, H_, H_, H_, H_);

            // x = rmsnorm(x+aob, nw1); xn = rmsnorm(x, nw2)
            rmsnorm_dual<<<M_, 256, 0, stream>>>(x, aob, nw + 1 * H_, nw + 2 * H_, x, xn);

            // hbuf = xn @ W1  [M,2I] fp32
            launch_mm<128, 128, float>(stream, xn, w1T, hbuf,
                                       M_, 2 * I_, H_, H_, H_, 2 * I_);

            silu_gate<<<dim3(8192), 256, 0, stream>>>(hbuf, gbuf);

            // aob = gbuf @ W2  (fp32)
            launch_mm<128, 128, float>(stream, gbuf, w2T, aob,
                                       M_, H_, I_, I_, I_, H_);

            rmsnorm_k<float><<<M_, 256, 0, stream>>>(x, aob, nw + 3 * H_, x);
        }
        state = x;
    }

    rmsnorm_k<float><<<M_, 256, 0, stream>>>(x, nullptr, FNW, out);
}

// Round 6
// 2324.543 us; speedup vs baseline: 9.5127x; 1.3148x over previous
//
#include <hip/hip_runtime.h>
#include <hip/hip_bf16.h>
#include <math.h>

// Problem constants (fixed by setup_inputs)
constexpr int B_  = 2;
constexpr int S_  = 1024;
constexpr int H_  = 1024;
constexpr int NH_ = 16;
constexpr int HD_ = 64;
constexpr int I_  = 4096;
constexpr int L_  = 4;
constexpr int M_  = B_ * S_;      // 2048 token rows
constexpr float EPS_ = 1e-6f;
constexpr int NUM_ITERS_ = 2;     // setup_inputs()["num_iterations"] == 2 (fixed input)
constexpr size_t PSTRIDE_ = (size_t)M_ * H_;   // split-K partial stride (elements)

typedef __attribute__((ext_vector_type(8))) short bf16x8;
typedef __attribute__((ext_vector_type(4))) float f32x4;

__device__ __forceinline__ short f2b(float x) {
    return __builtin_bit_cast(short, __float2bfloat16(x));
}
__device__ __forceinline__ float b2f(short s) {
    return __builtin_bit_cast(float, ((unsigned)(unsigned short)s) << 16);
}

__device__ __forceinline__ void lds_load16(void* lds, const void* g) {
    __builtin_amdgcn_global_load_lds(
        (const __attribute__((address_space(1))) void*)g,
        (__attribute__((address_space(3))) void*)lds, 16, 0, 0);
}

// ---------------------------------------------------------------------------
// Block reductions (wave64 shuffle + LDS across waves, blockDim = 256)
// ---------------------------------------------------------------------------
__device__ inline float block_reduce_sum(float v) {
    __shared__ float red[8];
    int lane = threadIdx.x & 63, wid = threadIdx.x >> 6;
#pragma unroll
    for (int o = 32; o; o >>= 1) v += __shfl_down(v, o);
    __syncthreads();
    if (lane == 0) red[wid] = v;
    __syncthreads();
    float s = 0.f;
    for (int i = 0; i < 4; ++i) s += red[i];
    return s;
}

__device__ inline float block_reduce_max(float v) {
    __shared__ float red[8];
    int lane = threadIdx.x & 63, wid = threadIdx.x >> 6;
#pragma unroll
    for (int o = 32; o; o >>= 1) v = fmaxf(v, __shfl_down(v, o));
    __syncthreads();
    if (lane == 0) red[wid] = v;
    __syncthreads();
    float s = -INFINITY;
    for (int i = 0; i < 4; ++i) s = fmaxf(s, red[i]);
    return s;
}

// ---------------------------------------------------------------------------
// bf16 MFMA GEMM (m97 structure): C[M,N] = A[M,K] @ B^T[N,K]^T
// A row-major (lda), Bt row-major (ldb), C row-major (ldc).
// 256 threads = 4 waves (2x2), tile BM x BN, BK=32, 16x16x32 MFMA.
// global_load_lds width-16 staging; k-slot XOR swizzle by (row>>1)&3.
// blockIdx.z = ((bb*NHb + hb) * KS + ks): batch (bb,hb) plus split-K slice ks.
// Slice ks covers K rows [ks*K/KS, (ks+1)*K/KS) and writes C + ks*sCk.
// Requires: M%BM==0, N%BN==0, (K/KS)%32==0, 16B-aligned rows.
// ---------------------------------------------------------------------------
template<int BM, int BN, typename OutT>
__global__ __launch_bounds__(256)
void gemm_mfma(const __hip_bfloat16* __restrict__ A,
               const __hip_bfloat16* __restrict__ Bt,
               OutT* __restrict__ C,
               int K, int lda, int ldb, int ldc,
               int NHb, int KS, long sCk,
               long sAb, long sAh, long sBb, long sBh, long sCb, long sCh)
{
    int z  = blockIdx.z;
    int ks = z % KS;
    int zz = z / KS;
    int hb = zz % NHb, bb = zz / NHb;
    A  += bb * sAb + hb * sAh;
    Bt += bb * sBb + hb * sBh;
    C  += bb * sCb + hb * sCh + (long)ks * sCk;

    const int kslice = K / KS;
    const int kbeg = ks * kslice, kend = kbeg + kslice;

    int bm = blockIdx.y * BM, bn = blockIdx.x * BN;

    __shared__ __align__(16) char smemA[BM * 64];   // [BM][32] bf16
    __shared__ __align__(16) char smemB[BN * 64];   // [BN][32] bf16

    const int t    = threadIdx.x;
    const int lane = t & 63;
    const int wv   = t >> 6;
    // staging: thread t covers row lr (within a 64-row chunk), swizzled k-slot
    const int lr  = t >> 2;                            // 0..63
    const int lsw = ((t & 3) ^ ((lr >> 1) & 3)) * 8;   // element offset in k

    constexpr int FM = BM / 32;   // 16-row frags per wave in M (wave tile = BM/2)
    constexpr int FN = BN / 32;
    const int wm = (wv >> 1) * (BM / 2);
    const int wn = (wv & 1) * (BN / 2);
    const int row16 = lane & 15;
    const int kg    = lane >> 4;

    f32x4 acc[FM][FN] = {};

    const char* Ab = (const char*)A;
    const char* Bb = (const char*)Bt;

    for (int k0 = kbeg; k0 < kend; k0 += 32) {
#pragma unroll
        for (int i = 0; i < BM / 64; ++i)
            lds_load16(smemA + i * 4096 + wv * 1024,
                       Ab + (((long)(bm + i * 64 + lr) * lda + k0 + lsw) << 1));
#pragma unroll
        for (int i = 0; i < BN / 64; ++i)
            lds_load16(smemB + i * 4096 + wv * 1024,
                       Bb + (((long)(bn + i * 64 + lr) * ldb + k0 + lsw) << 1));
        __syncthreads();

        bf16x8 af[FM], bfr[FN];
#pragma unroll
        for (int m = 0; m < FM; ++m) {
            int r = wm + m * 16 + row16;
            af[m] = *(const bf16x8*)(smemA + r * 64 + ((kg ^ ((r >> 1) & 3)) << 4));
        }
#pragma unroll
        for (int n = 0; n < FN; ++n) {
            int r = wn + n * 16 + row16;
            bfr[n] = *(const bf16x8*)(smemB + r * 64 + ((kg ^ ((r >> 1) & 3)) << 4));
        }
#pragma unroll
        for (int m = 0; m < FM; ++m)
#pragma unroll
            for (int n = 0; n < FN; ++n)
                acc[m][n] = __builtin_amdgcn_mfma_f32_16x16x32_bf16(
                                af[m], bfr[n], acc[m][n], 0, 0, 0);
        __syncthreads();
    }

    // epilogue: D row = (lane>>4)*4 + reg, col = lane&15  [m89/m91 layout]
#pragma unroll
    for (int m = 0; m < FM; ++m) {
#pragma unroll
        for (int n = 0; n < FN; ++n) {
#pragma unroll
            for (int r = 0; r < 4; ++r) {
                long row = bm + wm + m * 16 + kg * 4 + r;
                long col = bn + wn + n * 16 + row16;
                float val = acc[m][n][r];
                if constexpr (__is_same(OutT, __hip_bfloat16))
                    C[row * ldc + col] = __float2bfloat16(val);
                else
                    C[row * ldc + col] = val;
            }
        }
    }
}

template<int BM, int BN, typename OutT>
static inline void launch_mm(hipStream_t st,
                             const __hip_bfloat16* A, const __hip_bfloat16* Bt, OutT* C,
                             int M, int N, int K, int lda, int ldb, int ldc,
                             int nb = 1, int nh = 1,
                             long sAb = 0, long sAh = 0,
                             long sBb = 0, long sBh = 0,
                             long sCb = 0, long sCh = 0,
                             int ksplit = 1, long sCk = 0)
{
    dim3 grid(N / BN, M / BM, nb * nh * ksplit);
    gemm_mfma<BM, BN, OutT><<<grid, dim3(256), 0, st>>>(
        A, Bt, C, K, lda, ldb, ldc, nh, ksplit, sCk, sAb, sAh, sBb, sBh, sCb, sCh);
}

// ---------------------------------------------------------------------------
// Weight transpose + fp32->bf16: out[c][r] = (bf16)in[r][c]; in is [R][C]
// grid: (C/32, R/32, nz); 256 threads. R,C multiples of 32.
// ---------------------------------------------------------------------------
__global__ __launch_bounds__(256)
void transpose_w(const float* __restrict__ in, __hip_bfloat16* __restrict__ out,
                 int R, int C, long inz, long outz)
{
    in  += blockIdx.z * inz;
    out += blockIdx.z * outz;
    __shared__ float tile[32][33];
    int rb = blockIdx.y * 32, cb = blockIdx.x * 32;
    int tx = threadIdx.x & 31, ty = threadIdx.x >> 5;   // ty 0..7
#pragma unroll
    for (int i = 0; i < 32; i += 8)
        tile[ty + i][tx] = in[(long)(rb + ty + i) * C + cb + tx];
    __syncthreads();
#pragma unroll
    for (int i = 0; i < 32; i += 8)
        out[(long)(cb + ty + i) * R + rb + tx] = __float2bfloat16(tile[tx][ty + i]);
}

// ---------------------------------------------------------------------------
// V transpose per head: vT[z][d][s] = src[b*S+s][h*64+d], z = b*NH+h (bf16)
// src has row stride ldsrc. grid: (S/32, 64/32, B*NH); 256 threads
// ---------------------------------------------------------------------------
__global__ __launch_bounds__(256)
void transpose_v(const __hip_bfloat16* __restrict__ v, __hip_bfloat16* __restrict__ vT,
                 int ldsrc)
{
    int z = blockIdx.z, b = z >> 4, h = z & 15;
    __shared__ short tile[32][34];
    int sb = blockIdx.x * 32, db = blockIdx.y * 32;
    int tx = threadIdx.x & 31, ty = threadIdx.x >> 5;
    const __hip_bfloat16* src = v + (long)b * S_ * ldsrc + h * 64;
#pragma unroll
    for (int i = 0; i < 32; i += 8)
        tile[ty + i][tx] = __builtin_bit_cast(short, src[(long)(sb + ty + i) * ldsrc + db + tx]);
    __syncthreads();
    __hip_bfloat16* dst = vT + (long)z * 64 * S_;
#pragma unroll
    for (int i = 0; i < 32; i += 8)
        dst[(long)(db + ty + i) * S_ + sb + tx] =
            __builtin_bit_cast(__hip_bfloat16, tile[tx][ty + i]);
}

// ---------------------------------------------------------------------------
// RMSNorm with split-K partial reduction.
// v = (xb ? xb : 0) + sum_{p<P} parts[p]; if WX write raw v to xw;
// out = rmsnorm(v, w). One block per row, float4 per thread.
// ---------------------------------------------------------------------------
template<int P, bool WX, typename OutT>
__global__ __launch_bounds__(256)
void rmsnorm_p(const float* __restrict__ xb, const float* __restrict__ parts,
               const float* __restrict__ w, float* __restrict__ xw,
               OutT* __restrict__ out)
{
    long row = blockIdx.x;
    int t = threadIdx.x;
    long idx = row * H_ + t * 4;
    float4 v = {0.f, 0.f, 0.f, 0.f};
    if (xb) v = *(const float4*)&xb[idx];
#pragma unroll
    for (int p = 0; p < P; ++p) {
        float4 pv = *(const float4*)&parts[(size_t)p * PSTRIDE_ + idx];
        v.x += pv.x; v.y += pv.y; v.z += pv.z; v.w += pv.w;
    }
    if constexpr (WX) *(float4*)&xw[idx] = v;
    float ss = v.x * v.x + v.y * v.y + v.z * v.z + v.w * v.w;
    ss = block_reduce_sum(ss);
    float inv = rsqrtf(ss * (1.f / H_) + EPS_);
    float4 wv = *(const float4*)&w[t * 4];
    float4 y = {v.x * inv * wv.x, v.y * inv * wv.y, v.z * inv * wv.z, v.w * inv * wv.w};
    if constexpr (__is_same(OutT, __hip_bfloat16)) {
        short4 o = {f2b(y.x), f2b(y.y), f2b(y.z), f2b(y.w)};
        *(short4*)&out[idx] = o;
    } else {
        *(float4*)&out[idx] = y;
    }
}

// Fused dual norm with partials: x' = rmsnorm(x + sum parts, w1) [fp32 -> xout];
// xn = rmsnorm(x', w2) [bf16]
template<int P>
__global__ __launch_bounds__(256)
void rmsnorm_dual_p(const float* __restrict__ x, const float* __restrict__ parts,
                    const float* __restrict__ w1, const float* __restrict__ w2,
                    float* __restrict__ xout, __hip_bfloat16* __restrict__ xnout)
{
    long row = blockIdx.x;
    int t = threadIdx.x;
    long idx = row * H_ + t * 4;
    float4 v = *(const float4*)&x[idx];
#pragma unroll
    for (int p = 0; p < P; ++p) {
        float4 pv = *(const float4*)&parts[(size_t)p * PSTRIDE_ + idx];
        v.x += pv.x; v.y += pv.y; v.z += pv.z; v.w += pv.w;
    }
    float ss = v.x * v.x + v.y * v.y + v.z * v.z + v.w * v.w;
    ss = block_reduce_sum(ss);
    float inv = rsqrtf(ss * (1.f / H_) + EPS_);
    float4 w1v = *(const float4*)&w1[t * 4];
    float4 y = {v.x * inv * w1v.x, v.y * inv * w1v.y, v.z * inv * w1v.z, v.w * inv * w1v.w};
    *(float4*)&xout[idx] = y;
    float ss2 = y.x * y.x + y.y * y.y + y.z * y.z + y.w * y.w;
    ss2 = block_reduce_sum(ss2);
    float inv2 = rsqrtf(ss2 * (1.f / H_) + EPS_);
    float4 w2v = *(const float4*)&w2[t * 4];
    short4 o = {f2b(y.x * inv2 * w2v.x), f2b(y.y * inv2 * w2v.y),
                f2b(y.z * inv2 * w2v.z), f2b(y.w * inv2 * w2v.w)};
    *(short4*)&xnout[idx] = o;
}

// ---------------------------------------------------------------------------
// Causal softmax over bf16 score rows (in-place). blockIdx.x = (b,h,q).
// thread t owns elements t*4..t*4+3 of the 1024-long row. Masked -> 0.
// ---------------------------------------------------------------------------
__global__ __launch_bounds__(256)
void softmax_causal_bf16(__hip_bfloat16* __restrict__ sc, float scale)
{
    long r = blockIdx.x;
    int q = (int)(r % S_);
    __hip_bfloat16* row = sc + r * (long)S_;
    int t = threadIdx.x;
    short4 raw = *(const short4*)&row[t * 4];
    float f[4];
    f[0] = b2f(raw.x) * scale; f[1] = b2f(raw.y) * scale;
    f[2] = b2f(raw.z) * scale; f[3] = b2f(raw.w) * scale;
    float m = -INFINITY;
#pragma unroll
    for (int j = 0; j < 4; ++j)
        if (t * 4 + j <= q) m = fmaxf(m, f[j]);
    m = block_reduce_max(m);
    float e[4], sum = 0.f;
#pragma unroll
    for (int j = 0; j < 4; ++j) {
        e[j] = (t * 4 + j <= q) ? expf(f[j] - m) : 0.f;
        sum += e[j];
    }
    sum = block_reduce_sum(sum);
    float inv = 1.f / sum;
    short4 o = {f2b(e[0] * inv), f2b(e[1] * inv), f2b(e[2] * inv), f2b(e[3] * inv)};
    *(short4*)&row[t * 4] = o;
}

// ---------------------------------------------------------------------------
// concat -> bf16: cat[m, :H]=E[m], cat[m, H:2H]=state[m]
// ---------------------------------------------------------------------------
__global__ __launch_bounds__(256)
void concat_bf16(const float* __restrict__ E, const float* __restrict__ st,
                 __hip_bfloat16* __restrict__ cat)
{
    long n4 = (long)M_ * 2 * H_ / 4;
    for (long i = (long)blockIdx.x * blockDim.x + threadIdx.x; i < n4;
         i += (long)gridDim.x * blockDim.x) {
        long m = i / (2 * H_ / 4);
        long c4 = i % (2 * H_ / 4);
        const float* src = (c4 < H_ / 4) ? &E[m * H_ + c4 * 4]
                                         : &st[m * H_ + (c4 * 4 - H_)];
        float4 v = *(const float4*)src;
        short4 o = {f2b(v.x), f2b(v.y), f2b(v.z), f2b(v.w)};
        *(short4*)&cat[i * 4] = o;
    }
}

// ---------------------------------------------------------------------------
// silu-gate: g[m,i] = (bf16) silu(h[m,i]) * h[m,I+i]; h bf16 [M,2I]
// ---------------------------------------------------------------------------
__global__ __launch_bounds__(256)
void silu_gate(const __hip_bfloat16* __restrict__ h, __hip_bfloat16* __restrict__ g)
{
    long n4 = (long)M_ * I_ / 4;
    for (long i = (long)blockIdx.x * blockDim.x + threadIdx.x; i < n4;
         i += (long)gridDim.x * blockDim.x) {
        long m = i / (I_ / 4);
        long c = (i % (I_ / 4)) * 4;
        short4 gt = *(const short4*)&h[m * (2 * I_) + c];
        short4 vl = *(const short4*)&h[m * (2 * I_) + I_ + c];
        float gx = b2f(gt.x), gy = b2f(gt.y), gz = b2f(gt.z), gw = b2f(gt.w);
        float y0 = gx / (1.f + expf(-gx)) * b2f(vl.x);
        float y1 = gy / (1.f + expf(-gy)) * b2f(vl.y);
        float y2 = gz / (1.f + expf(-gz)) * b2f(vl.z);
        float y3 = gw / (1.f + expf(-gw)) * b2f(vl.w);
        short4 o = {f2b(y0), f2b(y1), f2b(y2), f2b(y3)};
        *(short4*)&g[m * I_ + c] = o;
    }
}

// ---------------------------------------------------------------------------
// Host launcher
// ---------------------------------------------------------------------------
extern "C" void kernel_launch(void* const* d_in, const int* in_sizes, int n_in,
                              void* d_out, int out_size, void* d_ws, size_t ws_size,
                              hipStream_t stream)
{
    const float* E   = (const float*)d_in[0];
    const float* st0 = (const float*)d_in[1];
    const float* Wa  = (const float*)d_in[2];
    const float* NW  = (const float*)d_in[3];
    const float* Wq  = (const float*)d_in[4];
    const float* Wk  = (const float*)d_in[5];
    const float* Wv  = (const float*)d_in[6];
    const float* Wo  = (const float*)d_in[7];
    const float* W1  = (const float*)d_in[8];
    const float* W2  = (const float*)d_in[9];
    const float* FNW = (const float*)d_in[10];
    float* out = (float*)d_out;
    (void)in_sizes; (void)n_in; (void)out_size;

    typedef __hip_bfloat16 bf16;

    // Resident-weight layout needs ~265 MB; fall back to per-layer W1/W2
    // staging (~189 MB, below the empirically-proven 206 MB ws floor) otherwise.
    const size_t RESIDENT_BYTES = 266000000;
    const bool resident = ws_size >= RESIDENT_BYTES;

    char* base = (char*)d_ws;
    size_t off = 0;
    auto alloc = [&](size_t bytes) -> char* {
        char* p = base + off;
        off += (bytes + 255) & ~(size_t)255;
        return p;
    };
    // bf16 transposed weights
    bf16* WaT   = (bf16*)alloc((size_t)H_ * 2 * H_ * 2);                    // 4 MB
    bf16* WqkvT = (bf16*)alloc((size_t)L_ * 3 * H_ * H_ * 2);               // 24 MB
    bf16* WoT   = (bf16*)alloc((size_t)L_ * H_ * H_ * 2);                   // 8 MB
    bf16* W1T   = (bf16*)alloc((resident ? (size_t)L_ : 1) * 2 * I_ * H_ * 2); // 64/16 MB
    bf16* W2T   = (bf16*)alloc((resident ? (size_t)L_ : 1) * H_ * I_ * 2);     // 32/8 MB
    // activations
    bf16*  cat  = (bf16*)alloc((size_t)M_ * 2 * H_ * 2);    // 8 MB
    float* x    = (float*)alloc((size_t)M_ * H_ * 4);       // 8 MB
    bf16*  xn   = (bf16*)alloc((size_t)M_ * H_ * 2);        // 4 MB
    bf16*  qkv  = (bf16*)alloc((size_t)M_ * 3 * H_ * 2);    // 12 MB [M][3H]
    bf16*  vT   = (bf16*)alloc((size_t)M_ * H_ * 2);        // 4 MB  [B*NH][64][S]
    bf16*  ob   = (bf16*)alloc((size_t)M_ * H_ * 2);        // 4 MB
    char*  scores_raw = alloc((size_t)B_ * NH_ * S_ * S_ * 2);  // 64 MB
    bf16*  scores = (bf16*)scores_raw;    // bf16 [B*NH][S][S] (attn probs)
    bf16*  hbuf   = (bf16*)scores_raw;    // bf16 [M][2I] = 32 MB, aliases scores
    float* parts  = (float*)scores_raw;   // split-K fp32 partials, 4 x 8 MB
    bf16*  gbuf   = (bf16*)alloc((size_t)M_ * I_ * 2);      // 16 MB

    // ---- one-time weight conversion/transpose ----
    transpose_w<<<dim3(H_ / 32, 2 * H_ / 32, 1), 256, 0, stream>>>(
        Wa, WaT, 2 * H_, H_, 0, 0);
    transpose_w<<<dim3(H_ / 32, H_ / 32, L_), 256, 0, stream>>>(
        Wq, WqkvT + 0 * H_ * H_, H_, H_, (long)H_ * H_, (long)3 * H_ * H_);
    transpose_w<<<dim3(H_ / 32, H_ / 32, L_), 256, 0, stream>>>(
        Wk, WqkvT + 1 * H_ * H_, H_, H_, (long)H_ * H_, (long)3 * H_ * H_);
    transpose_w<<<dim3(H_ / 32, H_ / 32, L_), 256, 0, stream>>>(
        Wv, WqkvT + 2 * H_ * H_, H_, H_, (long)H_ * H_, (long)3 * H_ * H_);
    transpose_w<<<dim3(H_ / 32, H_ / 32, L_), 256, 0, stream>>>(
        Wo, WoT, H_, H_, (long)H_ * H_, (long)H_ * H_);
    if (resident) {
        transpose_w<<<dim3(2 * I_ / 32, H_ / 32, L_), 256, 0, stream>>>(
            W1, W1T, H_, 2 * I_, (long)H_ * 2 * I_, (long)H_ * 2 * I_);
        transpose_w<<<dim3(H_ / 32, I_ / 32, L_), 256, 0, stream>>>(
            W2, W2T, I_, H_, (long)I_ * H_, (long)I_ * H_);
    }

    const float scale = 0.125f;   // 1/sqrt(HD)
    const float* state = st0;

    for (int it = 0; it < NUM_ITERS_; ++it) {
        concat_bf16<<<dim3(4096), 256, 0, stream>>>(E, state, cat);
        // adapter: parts[0..3] = cat @ Wa  (split-K x4; K=2048 -> 512/slice)
        launch_mm<128, 128, float>(stream, cat, WaT, parts,
                                   M_, H_, 2 * H_, 2 * H_, 2 * H_, H_,
                                   1, 1, 0, 0, 0, 0, 0, 0,
                                   4, (long)PSTRIDE_);

        for (int l = 0; l < L_; ++l) {
            const float* nw   = NW + (size_t)l * 4 * H_;
            const bf16* wqkvT = WqkvT + (size_t)l * 3 * H_ * H_;
            const bf16* woT   = WoT + (size_t)l * H_ * H_;
            const bf16* w1T;
            const bf16* w2T;
            if (resident) {
                w1T = W1T + (size_t)l * 2 * I_ * H_;
                w2T = W2T + (size_t)l * H_ * I_;
            } else {
                transpose_w<<<dim3(2 * I_ / 32, H_ / 32, 1), 256, 0, stream>>>(
                    W1 + (size_t)l * H_ * 2 * I_, W1T, H_, 2 * I_, 0, 0);
                transpose_w<<<dim3(H_ / 32, I_ / 32, 1), 256, 0, stream>>>(
                    W2 + (size_t)l * I_ * H_, W2T, I_, H_, 0, 0);
                w1T = W1T;
                w2T = W2T;
            }

            // layer-start norm: l==0 also materializes x = sum(adapter partials)
            if (l == 0)
                rmsnorm_p<4, true, bf16><<<M_, 256, 0, stream>>>(
                    nullptr, parts, nw + 0 * H_, x, xn);
            else
                rmsnorm_p<0, false, bf16><<<M_, 256, 0, stream>>>(
                    x, nullptr, nw + 0 * H_, nullptr, xn);

            // fused qkv = xn @ [Wq|Wk|Wv]   (bf16 out, [M][3H])
            launch_mm<128, 128, bf16>(stream, xn, wqkvT, qkv,
                                      M_, 3 * H_, H_, H_, H_, 3 * H_);

            // scores[b,h,q,k] = q . k  (q = qkv cols 0..H, k = cols H..2H)
            launch_mm<128, 128, bf16>(stream, qkv, qkv + H_, scores,
                                      S_, S_, HD_, 3 * H_, 3 * H_, S_,
                                      B_, NH_,
                                      (long)S_ * 3 * H_, 64,
                                      (long)S_ * 3 * H_, 64,
                                      (long)NH_ * S_ * S_, (long)S_ * S_);

            softmax_causal_bf16<<<B_ * NH_ * S_, 256, 0, stream>>>(scores, scale);

            // vT[z][d][s] from v section (cols 2H..3H)
            transpose_v<<<dim3(S_ / 32, 2, B_ * NH_), 256, 0, stream>>>(
                qkv + 2 * H_, vT, 3 * H_);

            // ob[b,q,h*64+d] = probs @ v
            launch_mm<128, 64, bf16>(stream, scores, vT, ob,
                                     S_, 64, S_, S_, S_, H_,
                                     B_, NH_,
                                     (long)NH_ * S_ * S_, (long)S_ * S_,
                                     (long)NH_ * 64 * S_, (long)64 * S_,
                                     (long)S_ * H_, 64);

            // attn partials = ob @ Wo  (split-K x4; K=1024 -> 256/slice)
            // scores (probs) are dead after PV; parts aliases that region.
            launch_mm<128, 128, float>(stream, ob, woT, parts,
                                       M_, H_, H_, H_, H_, H_,
                                       1, 1, 0, 0, 0, 0, 0, 0,
                                       4, (long)PSTRIDE_);

            // x = rmsnorm(x + sum parts, nw1); xn = rmsnorm(x, nw2)
            rmsnorm_dual_p<4><<<M_, 256, 0, stream>>>(
                x, parts, nw + 1 * H_, nw + 2 * H_, x, xn);

            // hbuf = xn @ W1  [M,2I] bf16 (overwrites parts region - dead)
            launch_mm<128, 128, bf16>(stream, xn, w1T, hbuf,
                                      M_, 2 * I_, H_, H_, H_, 2 * I_);

            silu_gate<<<dim3(8192), 256, 0, stream>>>(hbuf, gbuf);

            // mlp partials = gbuf @ W2 (split-K x4; K=4096 -> 1024/slice)
            // hbuf is dead after silu; parts aliases it.
            launch_mm<128, 128, float>(stream, gbuf, w2T, parts,
                                       M_, H_, I_, I_, I_, H_,
                                       1, 1, 0, 0, 0, 0, 0, 0,
                                       4, (long)PSTRIDE_);

            // x = rmsnorm(x + sum parts, nw3)
            rmsnorm_p<4, false, float><<<M_, 256, 0, stream>>>(
                x, parts, nw + 3 * H_, nullptr, x);
        }
        state = x;
    }

    rmsnorm_p<0, false, float><<<M_, 256, 0, stream>>>(
        x, nullptr, FNW, nullptr, out);
}

// Round 7
// 1997.522 us; speedup vs baseline: 11.0701x; 1.1637x over previous
//
#include <hip/hip_runtime.h>
#include <hip/hip_bf16.h>
#include <math.h>

// Problem constants (fixed by setup_inputs)
constexpr int B_  = 2;
constexpr int S_  = 1024;
constexpr int H_  = 1024;
constexpr int NH_ = 16;
constexpr int HD_ = 64;
constexpr int I_  = 4096;
constexpr int L_  = 4;
constexpr int M_  = B_ * S_;      // 2048 token rows
constexpr float EPS_ = 1e-6f;
constexpr int NUM_ITERS_ = 2;     // setup_inputs()["num_iterations"] == 2 (fixed input)
constexpr size_t PSTRIDE_ = (size_t)M_ * H_;   // split-K partial stride (elements)

typedef __attribute__((ext_vector_type(8))) short bf16x8;
typedef __attribute__((ext_vector_type(4))) float f32x4;

__device__ __forceinline__ short f2b(float x) {
    return __builtin_bit_cast(short, __float2bfloat16(x));
}
__device__ __forceinline__ float b2f(short s) {
    return __builtin_bit_cast(float, ((unsigned)(unsigned short)s) << 16);
}

__device__ __forceinline__ void lds_load16(void* lds, const void* g) {
    __builtin_amdgcn_global_load_lds(
        (const __attribute__((address_space(1))) void*)g,
        (__attribute__((address_space(3))) void*)lds, 16, 0, 0);
}

// ---------------------------------------------------------------------------
// Block reductions (wave64 shuffle + LDS across waves, blockDim = 256)
// ---------------------------------------------------------------------------
__device__ inline float block_reduce_sum(float v) {
    __shared__ float red[8];
    int lane = threadIdx.x & 63, wid = threadIdx.x >> 6;
#pragma unroll
    for (int o = 32; o; o >>= 1) v += __shfl_down(v, o);
    __syncthreads();
    if (lane == 0) red[wid] = v;
    __syncthreads();
    float s = 0.f;
    for (int i = 0; i < 4; ++i) s += red[i];
    return s;
}

// ---------------------------------------------------------------------------
// bf16 MFMA GEMM (m97 structure): C[M,N] = A[M,K] @ B^T[N,K]^T
// A row-major (lda), Bt row-major (ldb), C row-major (ldc).
// 256 threads = 4 waves (2x2), tile BM x BN, BK=32, 16x16x32 MFMA.
// global_load_lds width-16 staging; k-slot XOR swizzle by (row>>1)&3.
// blockIdx.z = ((bb*NHb + hb) * KS + ks): batch (bb,hb) plus split-K slice ks.
// ---------------------------------------------------------------------------
template<int BM, int BN, typename OutT>
__global__ __launch_bounds__(256)
void gemm_mfma(const __hip_bfloat16* __restrict__ A,
               const __hip_bfloat16* __restrict__ Bt,
               OutT* __restrict__ C,
               int K, int lda, int ldb, int ldc,
               int NHb, int KS, long sCk,
               long sAb, long sAh, long sBb, long sBh, long sCb, long sCh)
{
    int z  = blockIdx.z;
    int ks = z % KS;
    int zz = z / KS;
    int hb = zz % NHb, bb = zz / NHb;
    A  += bb * sAb + hb * sAh;
    Bt += bb * sBb + hb * sBh;
    C  += bb * sCb + hb * sCh + (long)ks * sCk;

    const int kslice = K / KS;
    const int kbeg = ks * kslice, kend = kbeg + kslice;

    int bm = blockIdx.y * BM, bn = blockIdx.x * BN;

    __shared__ __align__(16) char smemA[BM * 64];   // [BM][32] bf16
    __shared__ __align__(16) char smemB[BN * 64];   // [BN][32] bf16

    const int t    = threadIdx.x;
    const int lane = t & 63;
    const int wv   = t >> 6;
    const int lr  = t >> 2;                            // 0..63
    const int lsw = ((t & 3) ^ ((lr >> 1) & 3)) * 8;   // element offset in k

    constexpr int FM = BM / 32;
    constexpr int FN = BN / 32;
    const int wm = (wv >> 1) * (BM / 2);
    const int wn = (wv & 1) * (BN / 2);
    const int row16 = lane & 15;
    const int kg    = lane >> 4;

    f32x4 acc[FM][FN] = {};

    const char* Ab = (const char*)A;
    const char* Bb = (const char*)Bt;

    for (int k0 = kbeg; k0 < kend; k0 += 32) {
#pragma unroll
        for (int i = 0; i < BM / 64; ++i)
            lds_load16(smemA + i * 4096 + wv * 1024,
                       Ab + (((long)(bm + i * 64 + lr) * lda + k0 + lsw) << 1));
#pragma unroll
        for (int i = 0; i < BN / 64; ++i)
            lds_load16(smemB + i * 4096 + wv * 1024,
                       Bb + (((long)(bn + i * 64 + lr) * ldb + k0 + lsw) << 1));
        __syncthreads();

        bf16x8 af[FM], bfr[FN];
#pragma unroll
        for (int m = 0; m < FM; ++m) {
            int r = wm + m * 16 + row16;
            af[m] = *(const bf16x8*)(smemA + r * 64 + ((kg ^ ((r >> 1) & 3)) << 4));
        }
#pragma unroll
        for (int n = 0; n < FN; ++n) {
            int r = wn + n * 16 + row16;
            bfr[n] = *(const bf16x8*)(smemB + r * 64 + ((kg ^ ((r >> 1) & 3)) << 4));
        }
#pragma unroll
        for (int m = 0; m < FM; ++m)
#pragma unroll
            for (int n = 0; n < FN; ++n)
                acc[m][n] = __builtin_amdgcn_mfma_f32_16x16x32_bf16(
                                af[m], bfr[n], acc[m][n], 0, 0, 0);
        __syncthreads();
    }

#pragma unroll
    for (int m = 0; m < FM; ++m) {
#pragma unroll
        for (int n = 0; n < FN; ++n) {
#pragma unroll
            for (int r = 0; r < 4; ++r) {
                long row = bm + wm + m * 16 + kg * 4 + r;
                long col = bn + wn + n * 16 + row16;
                float val = acc[m][n][r];
                if constexpr (__is_same(OutT, __hip_bfloat16))
                    C[row * ldc + col] = __float2bfloat16(val);
                else
                    C[row * ldc + col] = val;
            }
        }
    }
}

template<int BM, int BN, typename OutT>
static inline void launch_mm(hipStream_t st,
                             const __hip_bfloat16* A, const __hip_bfloat16* Bt, OutT* C,
                             int M, int N, int K, int lda, int ldb, int ldc,
                             int nb = 1, int nh = 1,
                             long sAb = 0, long sAh = 0,
                             long sBb = 0, long sBh = 0,
                             long sCb = 0, long sCh = 0,
                             int ksplit = 1, long sCk = 0)
{
    dim3 grid(N / BN, M / BM, nb * nh * ksplit);
    gemm_mfma<BM, BN, OutT><<<grid, dim3(256), 0, st>>>(
        A, Bt, C, K, lda, ldb, ldc, nh, ksplit, sCk, sAb, sAh, sBb, sBh, sCb, sCh);
}

// ---------------------------------------------------------------------------
// Fused causal flash attention.
// grid (S/128, B*NH); 256 threads = 4 waves; wave w owns q rows [qt*128+w*32,+32).
// Q,K read from qkv [M][3H] (Q cols h*64, K cols H+h*64); V from vT[z][64][S].
// Online softmax in fp32; P via XOR-swizzled LDS; out ob[M][H] bf16.
// ---------------------------------------------------------------------------
__global__ __launch_bounds__(256)
void flash_attn(const __hip_bfloat16* __restrict__ qkv,
                const __hip_bfloat16* __restrict__ vT,
                __hip_bfloat16* __restrict__ ob, float scale)
{
    constexpr int KB = 128;
    const int qt = blockIdx.x;          // q tile 0..7
    const int z  = blockIdx.y;          // 0..31
    const int b  = z >> 4, h = z & 15;

    __shared__ __align__(16) char sK[KB * 128];      // [kv][64 d] bf16, swz
    __shared__ __align__(16) char sV[64 * 256];      // [d][128 kv] bf16, swz
    __shared__ __align__(16) char sP[4][32 * 256];   // per wave [32 q][128 kv]

    const int t    = threadIdx.x;
    const int lane = t & 63;
    const int wv   = t >> 6;
    const int l15  = lane & 15;
    const int kg   = lane >> 4;

    const long qbase = (long)b * S_ * 3 * H_;   // batch offset (elements)
    const int wq0 = qt * 128 + wv * 32;         // wave's first q row (in-seq)

    // Q fragments: [qb][ks], A-row = l15, d = ks*32 + kg*8
    bf16x8 qf[2][2];
#pragma unroll
    for (int qb = 0; qb < 2; ++qb)
#pragma unroll
        for (int ks = 0; ks < 2; ++ks)
            qf[qb][ks] = *(const bf16x8*)&qkv[qbase +
                (long)(wq0 + qb * 16 + l15) * (3 * H_) + h * 64 + ks * 32 + kg * 8];

    f32x4 oacc[2][4] = {};          // [qb][db]
    float mrow[2][4], lrow[2][4];
#pragma unroll
    for (int qb = 0; qb < 2; ++qb)
#pragma unroll
        for (int r = 0; r < 4; ++r) { mrow[qb][r] = -INFINITY; lrow[qb][r] = 0.f; }

    const int ntiles = qt + 1;
    for (int tile = 0; tile < ntiles; ++tile) {
        const int kv0 = tile * KB;
        __syncthreads();   // all waves done reading previous K/V
        // stage K tile [128][64]: row = kv, 128 B/row; dest linear, src pre-swizzled
#pragma unroll
        for (int rnd = 0; rnd < 4; ++rnd) {
            int row = rnd * 32 + (t >> 3);
            int cb  = ((t & 7) * 16) ^ ((row & 7) << 4);
            lds_load16(sK + rnd * 4096 + wv * 1024,
                       (const char*)qkv +
                       ((qbase + (long)(kv0 + row) * (3 * H_) + H_ + h * 64) << 1) + cb);
        }
        // stage V tile [64][128] from vT: row = d, 256 B/row
#pragma unroll
        for (int rnd = 0; rnd < 4; ++rnd) {
            int row = rnd * 16 + (t >> 4);
            int cb  = ((t & 15) * 16) ^ ((row & 7) << 4);
            lds_load16(sV + rnd * 4096 + wv * 1024,
                       (const char*)vT + (((long)(z * 64 + row) * S_ + kv0) << 1) + cb);
        }
        __syncthreads();   // staging landed (vmcnt drained by barrier)

        if (kv0 > wq0 + 31) continue;   // tile fully above diagonal for this wave

        // ---- QK^T: s[qb][cb], C row = q (kg*4+r), col = kv (l15) ----
        f32x4 s[2][8] = {};
#pragma unroll
        for (int cb = 0; cb < 8; ++cb) {
#pragma unroll
            for (int ks = 0; ks < 2; ++ks) {
                int krow = cb * 16 + l15;
                bf16x8 kf = *(const bf16x8*)(sK + krow * 128 +
                                             ((ks * 64 + kg * 16) ^ ((krow & 7) << 4)));
#pragma unroll
                for (int qb = 0; qb < 2; ++qb)
                    s[qb][cb] = __builtin_amdgcn_mfma_f32_16x16x32_bf16(
                                    qf[qb][ks], kf, s[qb][cb], 0, 0, 0);
            }
        }

        // ---- scale + causal mask + row-max ----
        float tmax[2][4];
#pragma unroll
        for (int qb = 0; qb < 2; ++qb)
#pragma unroll
            for (int r = 0; r < 4; ++r) tmax[qb][r] = -INFINITY;
#pragma unroll
        for (int qb = 0; qb < 2; ++qb) {
#pragma unroll
            for (int cb = 0; cb < 8; ++cb) {
#pragma unroll
                for (int r = 0; r < 4; ++r) {
                    float v = s[qb][cb][r] * scale;
                    int kq = kv0 + cb * 16 + l15;
                    int qq = wq0 + qb * 16 + kg * 4 + r;
                    v = (kq <= qq) ? v : -INFINITY;
                    s[qb][cb][r] = v;
                    tmax[qb][r] = fmaxf(tmax[qb][r], v);
                }
            }
        }
#pragma unroll
        for (int qb = 0; qb < 2; ++qb)
#pragma unroll
            for (int r = 0; r < 4; ++r) {
                float v = tmax[qb][r];
                v = fmaxf(v, __shfl_xor(v, 1));
                v = fmaxf(v, __shfl_xor(v, 2));
                v = fmaxf(v, __shfl_xor(v, 4));
                v = fmaxf(v, __shfl_xor(v, 8));
                tmax[qb][r] = v;
            }

        // ---- online-softmax update: rescale O, exp, sum, P -> LDS(bf16) ----
        float tsum[2][4];
#pragma unroll
        for (int qb = 0; qb < 2; ++qb) {
#pragma unroll
            for (int r = 0; r < 4; ++r) {
                float mn = fmaxf(mrow[qb][r], tmax[qb][r]);
                float c  = __expf(mrow[qb][r] - mn);   // first tile: exp(-inf)=0
                mrow[qb][r] = mn;
                lrow[qb][r] *= c;
                tsum[qb][r] = 0.f;
#pragma unroll
                for (int db = 0; db < 4; ++db) oacc[qb][db][r] *= c;
            }
        }
#pragma unroll
        for (int qb = 0; qb < 2; ++qb) {
#pragma unroll
            for (int cb = 0; cb < 8; ++cb) {
#pragma unroll
                for (int r = 0; r < 4; ++r) {
                    float p = __expf(s[qb][cb][r] - mrow[qb][r]);  // masked -> 0
                    tsum[qb][r] += p;
                    int qloc = qb * 16 + kg * 4 + r;
                    int kvb  = (cb * 16 + l15) * 2;
                    *(short*)(sP[wv] + qloc * 256 + (kvb ^ ((qloc & 7) << 4))) = f2b(p);
                }
            }
        }
#pragma unroll
        for (int qb = 0; qb < 2; ++qb)
#pragma unroll
            for (int r = 0; r < 4; ++r) {
                float v = tsum[qb][r];
                v += __shfl_xor(v, 1);
                v += __shfl_xor(v, 2);
                v += __shfl_xor(v, 4);
                v += __shfl_xor(v, 8);
                lrow[qb][r] += v;
            }

        // ---- PV: oacc += P @ V  (A = P from own-wave LDS, B = V^T tile) ----
#pragma unroll
        for (int ks2 = 0; ks2 < 4; ++ks2) {
            bf16x8 pf[2];
#pragma unroll
            for (int qb = 0; qb < 2; ++qb) {
                int qloc = qb * 16 + l15;
                pf[qb] = *(const bf16x8*)(sP[wv] + qloc * 256 +
                                          ((ks2 * 64 + kg * 16) ^ ((qloc & 7) << 4)));
            }
#pragma unroll
            for (int db = 0; db < 4; ++db) {
                int drow = db * 16 + l15;
                bf16x8 vf = *(const bf16x8*)(sV + drow * 256 +
                                             ((ks2 * 64 + kg * 16) ^ ((drow & 7) << 4)));
#pragma unroll
                for (int qb = 0; qb < 2; ++qb)
                    oacc[qb][db] = __builtin_amdgcn_mfma_f32_16x16x32_bf16(
                                       pf[qb], vf, oacc[qb][db], 0, 0, 0);
            }
        }
    }

    // ---- epilogue: O /= l, write bf16 to ob[M][H] ----
#pragma unroll
    for (int qb = 0; qb < 2; ++qb) {
#pragma unroll
        for (int r = 0; r < 4; ++r) {
            float inv = 1.f / lrow[qb][r];
            long row = (long)b * S_ + wq0 + qb * 16 + kg * 4 + r;
#pragma unroll
            for (int db = 0; db < 4; ++db) {
                long col = h * 64 + db * 16 + l15;
                ob[row * H_ + col] = __float2bfloat16(oacc[qb][db][r] * inv);
            }
        }
    }
}

// ---------------------------------------------------------------------------
// Weight transpose + fp32->bf16: out[c][r] = (bf16)in[r][c]; in is [R][C]
// ---------------------------------------------------------------------------
__global__ __launch_bounds__(256)
void transpose_w(const float* __restrict__ in, __hip_bfloat16* __restrict__ out,
                 int R, int C, long inz, long outz)
{
    in  += blockIdx.z * inz;
    out += blockIdx.z * outz;
    __shared__ float tile[32][33];
    int rb = blockIdx.y * 32, cb = blockIdx.x * 32;
    int tx = threadIdx.x & 31, ty = threadIdx.x >> 5;
#pragma unroll
    for (int i = 0; i < 32; i += 8)
        tile[ty + i][tx] = in[(long)(rb + ty + i) * C + cb + tx];
    __syncthreads();
#pragma unroll
    for (int i = 0; i < 32; i += 8)
        out[(long)(cb + ty + i) * R + rb + tx] = __float2bfloat16(tile[tx][ty + i]);
}

// ---------------------------------------------------------------------------
// V transpose per head: vT[z][d][s] = src[b*S+s][h*64+d], z = b*NH+h (bf16)
// ---------------------------------------------------------------------------
__global__ __launch_bounds__(256)
void transpose_v(const __hip_bfloat16* __restrict__ v, __hip_bfloat16* __restrict__ vT,
                 int ldsrc)
{
    int z = blockIdx.z, b = z >> 4, h = z & 15;
    __shared__ short tile[32][34];
    int sb = blockIdx.x * 32, db = blockIdx.y * 32;
    int tx = threadIdx.x & 31, ty = threadIdx.x >> 5;
    const __hip_bfloat16* src = v + (long)b * S_ * ldsrc + h * 64;
#pragma unroll
    for (int i = 0; i < 32; i += 8)
        tile[ty + i][tx] = __builtin_bit_cast(short, src[(long)(sb + ty + i) * ldsrc + db + tx]);
    __syncthreads();
    __hip_bfloat16* dst = vT + (long)z * 64 * S_;
#pragma unroll
    for (int i = 0; i < 32; i += 8)
        dst[(long)(db + ty + i) * S_ + sb + tx] =
            __builtin_bit_cast(__hip_bfloat16, tile[tx][ty + i]);
}

// ---------------------------------------------------------------------------
// RMSNorm with split-K partial reduction.
// ---------------------------------------------------------------------------
template<int P, bool WX, typename OutT>
__global__ __launch_bounds__(256)
void rmsnorm_p(const float* __restrict__ xb, const float* __restrict__ parts,
               const float* __restrict__ w, float* __restrict__ xw,
               OutT* __restrict__ out)
{
    long row = blockIdx.x;
    int t = threadIdx.x;
    long idx = row * H_ + t * 4;
    float4 v = {0.f, 0.f, 0.f, 0.f};
    if (xb) v = *(const float4*)&xb[idx];
#pragma unroll
    for (int p = 0; p < P; ++p) {
        float4 pv = *(const float4*)&parts[(size_t)p * PSTRIDE_ + idx];
        v.x += pv.x; v.y += pv.y; v.z += pv.z; v.w += pv.w;
    }
    if constexpr (WX) *(float4*)&xw[idx] = v;
    float ss = v.x * v.x + v.y * v.y + v.z * v.z + v.w * v.w;
    ss = block_reduce_sum(ss);
    float inv = rsqrtf(ss * (1.f / H_) + EPS_);
    float4 wv = *(const float4*)&w[t * 4];
    float4 y = {v.x * inv * wv.x, v.y * inv * wv.y, v.z * inv * wv.z, v.w * inv * wv.w};
    if constexpr (__is_same(OutT, __hip_bfloat16)) {
        short4 o = {f2b(y.x), f2b(y.y), f2b(y.z), f2b(y.w)};
        *(short4*)&out[idx] = o;
    } else {
        *(float4*)&out[idx] = y;
    }
}

// Fused dual norm with partials
template<int P>
__global__ __launch_bounds__(256)
void rmsnorm_dual_p(const float* __restrict__ x, const float* __restrict__ parts,
                    const float* __restrict__ w1, const float* __restrict__ w2,
                    float* __restrict__ xout, __hip_bfloat16* __restrict__ xnout)
{
    long row = blockIdx.x;
    int t = threadIdx.x;
    long idx = row * H_ + t * 4;
    float4 v = *(const float4*)&x[idx];
#pragma unroll
    for (int p = 0; p < P; ++p) {
        float4 pv = *(const float4*)&parts[(size_t)p * PSTRIDE_ + idx];
        v.x += pv.x; v.y += pv.y; v.z += pv.z; v.w += pv.w;
    }
    float ss = v.x * v.x + v.y * v.y + v.z * v.z + v.w * v.w;
    ss = block_reduce_sum(ss);
    float inv = rsqrtf(ss * (1.f / H_) + EPS_);
    float4 w1v = *(const float4*)&w1[t * 4];
    float4 y = {v.x * inv * w1v.x, v.y * inv * w1v.y, v.z * inv * w1v.z, v.w * inv * w1v.w};
    *(float4*)&xout[idx] = y;
    float ss2 = y.x * y.x + y.y * y.y + y.z * y.z + y.w * y.w;
    ss2 = block_reduce_sum(ss2);
    float inv2 = rsqrtf(ss2 * (1.f / H_) + EPS_);
    float4 w2v = *(const float4*)&w2[t * 4];
    short4 o = {f2b(y.x * inv2 * w2v.x), f2b(y.y * inv2 * w2v.y),
                f2b(y.z * inv2 * w2v.z), f2b(y.w * inv2 * w2v.w)};
    *(short4*)&xnout[idx] = o;
}

// ---------------------------------------------------------------------------
// concat -> bf16
// ---------------------------------------------------------------------------
__global__ __launch_bounds__(256)
void concat_bf16(const float* __restrict__ E, const float* __restrict__ st,
                 __hip_bfloat16* __restrict__ cat)
{
    long n4 = (long)M_ * 2 * H_ / 4;
    for (long i = (long)blockIdx.x * blockDim.x + threadIdx.x; i < n4;
         i += (long)gridDim.x * blockDim.x) {
        long m = i / (2 * H_ / 4);
        long c4 = i % (2 * H_ / 4);
        const float* src = (c4 < H_ / 4) ? &E[m * H_ + c4 * 4]
                                         : &st[m * H_ + (c4 * 4 - H_)];
        float4 v = *(const float4*)src;
        short4 o = {f2b(v.x), f2b(v.y), f2b(v.z), f2b(v.w)};
        *(short4*)&cat[i * 4] = o;
    }
}

// ---------------------------------------------------------------------------
// silu-gate: g[m,i] = (bf16) silu(h[m,i]) * h[m,I+i]; h bf16 [M,2I]
// ---------------------------------------------------------------------------
__global__ __launch_bounds__(256)
void silu_gate(const __hip_bfloat16* __restrict__ h, __hip_bfloat16* __restrict__ g)
{
    long n4 = (long)M_ * I_ / 4;
    for (long i = (long)blockIdx.x * blockDim.x + threadIdx.x; i < n4;
         i += (long)gridDim.x * blockDim.x) {
        long m = i / (I_ / 4);
        long c = (i % (I_ / 4)) * 4;
        short4 gt = *(const short4*)&h[m * (2 * I_) + c];
        short4 vl = *(const short4*)&h[m * (2 * I_) + I_ + c];
        float gx = b2f(gt.x), gy = b2f(gt.y), gz = b2f(gt.z), gw = b2f(gt.w);
        float y0 = gx / (1.f + expf(-gx)) * b2f(vl.x);
        float y1 = gy / (1.f + expf(-gy)) * b2f(vl.y);
        float y2 = gz / (1.f + expf(-gz)) * b2f(vl.z);
        float y3 = gw / (1.f + expf(-gw)) * b2f(vl.w);
        short4 o = {f2b(y0), f2b(y1), f2b(y2), f2b(y3)};
        *(short4*)&g[m * I_ + c] = o;
    }
}

// ---------------------------------------------------------------------------
// Host launcher
// ---------------------------------------------------------------------------
extern "C" void kernel_launch(void* const* d_in, const int* in_sizes, int n_in,
                              void* d_out, int out_size, void* d_ws, size_t ws_size,
                              hipStream_t stream)
{
    const float* E   = (const float*)d_in[0];
    const float* st0 = (const float*)d_in[1];
    const float* Wa  = (const float*)d_in[2];
    const float* NW  = (const float*)d_in[3];
    const float* Wq  = (const float*)d_in[4];
    const float* Wk  = (const float*)d_in[5];
    const float* Wv  = (const float*)d_in[6];
    const float* Wo  = (const float*)d_in[7];
    const float* W1  = (const float*)d_in[8];
    const float* W2  = (const float*)d_in[9];
    const float* FNW = (const float*)d_in[10];
    float* out = (float*)d_out;
    (void)in_sizes; (void)n_in; (void)out_size;

    typedef __hip_bfloat16 bf16;

    const size_t RESIDENT_BYTES = 266000000;
    const bool resident = ws_size >= RESIDENT_BYTES;

    char* base = (char*)d_ws;
    size_t off = 0;
    auto alloc = [&](size_t bytes) -> char* {
        char* p = base + off;
        off += (bytes + 255) & ~(size_t)255;
        return p;
    };
    // bf16 transposed weights
    bf16* WaT   = (bf16*)alloc((size_t)H_ * 2 * H_ * 2);                       // 4 MB
    bf16* WqkvT = (bf16*)alloc((size_t)L_ * 3 * H_ * H_ * 2);                  // 24 MB
    bf16* WoT   = (bf16*)alloc((size_t)L_ * H_ * H_ * 2);                      // 8 MB
    bf16* W1T   = (bf16*)alloc((resident ? (size_t)L_ : 1) * 2 * I_ * H_ * 2); // 64/16 MB
    bf16* W2T   = (bf16*)alloc((resident ? (size_t)L_ : 1) * H_ * I_ * 2);     // 32/8 MB
    // activations
    bf16*  cat  = (bf16*)alloc((size_t)M_ * 2 * H_ * 2);    // 8 MB
    float* x    = (float*)alloc((size_t)M_ * H_ * 4);       // 8 MB
    bf16*  xn   = (bf16*)alloc((size_t)M_ * H_ * 2);        // 4 MB
    bf16*  qkv  = (bf16*)alloc((size_t)M_ * 3 * H_ * 2);    // 12 MB [M][3H]
    bf16*  vT   = (bf16*)alloc((size_t)M_ * H_ * 2);        // 4 MB  [B*NH][64][S]
    bf16*  ob   = (bf16*)alloc((size_t)M_ * H_ * 2);        // 4 MB
    char*  big  = alloc((size_t)M_ * 2 * I_ * 4 > (size_t)4 * PSTRIDE_ * 4
                        ? (size_t)M_ * 2 * I_ * 4 : (size_t)4 * PSTRIDE_ * 4); // 64 MB
    bf16*  hbuf   = (bf16*)big;           // bf16 [M][2I] = 32 MB
    float* parts  = (float*)big;          // split-K fp32 partials, 4 x 8 MB
    bf16*  gbuf   = (bf16*)alloc((size_t)M_ * I_ * 2);      // 16 MB

    // ---- one-time weight conversion/transpose ----
    transpose_w<<<dim3(H_ / 32, 2 * H_ / 32, 1), 256, 0, stream>>>(
        Wa, WaT, 2 * H_, H_, 0, 0);
    transpose_w<<<dim3(H_ / 32, H_ / 32, L_), 256, 0, stream>>>(
        Wq, WqkvT + 0 * H_ * H_, H_, H_, (long)H_ * H_, (long)3 * H_ * H_);
    transpose_w<<<dim3(H_ / 32, H_ / 32, L_), 256, 0, stream>>>(
        Wk, WqkvT + 1 * H_ * H_, H_, H_, (long)H_ * H_, (long)3 * H_ * H_);
    transpose_w<<<dim3(H_ / 32, H_ / 32, L_), 256, 0, stream>>>(
        Wv, WqkvT + 2 * H_ * H_, H_, H_, (long)H_ * H_, (long)3 * H_ * H_);
    transpose_w<<<dim3(H_ / 32, H_ / 32, L_), 256, 0, stream>>>(
        Wo, WoT, H_, H_, (long)H_ * H_, (long)H_ * H_);
    if (resident) {
        transpose_w<<<dim3(2 * I_ / 32, H_ / 32, L_), 256, 0, stream>>>(
            W1, W1T, H_, 2 * I_, (long)H_ * 2 * I_, (long)H_ * 2 * I_);
        transpose_w<<<dim3(H_ / 32, I_ / 32, L_), 256, 0, stream>>>(
            W2, W2T, I_, H_, (long)I_ * H_, (long)I_ * H_);
    }

    const float scale = 0.125f;   // 1/sqrt(HD)
    const float* state = st0;

    for (int it = 0; it < NUM_ITERS_; ++it) {
        concat_bf16<<<dim3(4096), 256, 0, stream>>>(E, state, cat);
        // adapter: parts[0..3] = cat @ Wa  (split-K x4)
        launch_mm<128, 128, float>(stream, cat, WaT, parts,
                                   M_, H_, 2 * H_, 2 * H_, 2 * H_, H_,
                                   1, 1, 0, 0, 0, 0, 0, 0,
                                   4, (long)PSTRIDE_);

        for (int l = 0; l < L_; ++l) {
            const float* nw   = NW + (size_t)l * 4 * H_;
            const bf16* wqkvT = WqkvT + (size_t)l * 3 * H_ * H_;
            const bf16* woT   = WoT + (size_t)l * H_ * H_;
            const bf16* w1T;
            const bf16* w2T;
            if (resident) {
                w1T = W1T + (size_t)l * 2 * I_ * H_;
                w2T = W2T + (size_t)l * H_ * I_;
            } else {
                transpose_w<<<dim3(2 * I_ / 32, H_ / 32, 1), 256, 0, stream>>>(
                    W1 + (size_t)l * H_ * 2 * I_, W1T, H_, 2 * I_, 0, 0);
                transpose_w<<<dim3(H_ / 32, I_ / 32, 1), 256, 0, stream>>>(
                    W2 + (size_t)l * I_ * H_, W2T, I_, H_, 0, 0);
                w1T = W1T;
                w2T = W2T;
            }

            if (l == 0)
                rmsnorm_p<4, true, bf16><<<M_, 256, 0, stream>>>(
                    nullptr, parts, nw + 0 * H_, x, xn);
            else
                rmsnorm_p<0, false, bf16><<<M_, 256, 0, stream>>>(
                    x, nullptr, nw + 0 * H_, nullptr, xn);

            // fused qkv = xn @ [Wq|Wk|Wv]
            launch_mm<128, 128, bf16>(stream, xn, wqkvT, qkv,
                                      M_, 3 * H_, H_, H_, H_, 3 * H_);

            // vT[z][d][s] from v section (cols 2H..3H)
            transpose_v<<<dim3(S_ / 32, 2, B_ * NH_), 256, 0, stream>>>(
                qkv + 2 * H_, vT, 3 * H_);

            // fused causal flash attention -> ob
            flash_attn<<<dim3(S_ / 128, B_ * NH_), 256, 0, stream>>>(
                qkv, vT, ob, scale);

            // attn partials = ob @ Wo  (split-K x4)
            launch_mm<128, 128, float>(stream, ob, woT, parts,
                                       M_, H_, H_, H_, H_, H_,
                                       1, 1, 0, 0, 0, 0, 0, 0,
                                       4, (long)PSTRIDE_);

            // x = rmsnorm(x + sum parts, nw1); xn = rmsnorm(x, nw2)
            rmsnorm_dual_p<4><<<M_, 256, 0, stream>>>(
                x, parts, nw + 1 * H_, nw + 2 * H_, x, xn);

            // hbuf = xn @ W1  [M,2I] bf16
            launch_mm<128, 128, bf16>(stream, xn, w1T, hbuf,
                                      M_, 2 * I_, H_, H_, H_, 2 * I_);

            silu_gate<<<dim3(8192), 256, 0, stream>>>(hbuf, gbuf);

            // mlp partials = gbuf @ W2 (split-K x4)
            launch_mm<128, 128, float>(stream, gbuf, w2T, parts,
                                       M_, H_, I_, I_, I_, H_,
                                       1, 1, 0, 0, 0, 0, 0, 0,
                                       4, (long)PSTRIDE_);

            // x = rmsnorm(x + sum parts, nw3)
            rmsnorm_p<4, false, float><<<M_, 256, 0, stream>>>(
                x, parts, nw + 3 * H_, nullptr, x);
        }
        state = x;
    }

    rmsnorm_p<0, false, float><<<M_, 256, 0, stream>>>(
        x, nullptr, FNW, nullptr, out);
}